// Round 1
// baseline (2061.209 us; speedup 1.0000x reference)
//
#include <hip/hip_runtime.h>
#include <math.h>

#define DIM 64

// ---------------- edge softmax (per edge set) ----------------

__global__ void edge_max_kernel(const float* __restrict__ raw,
                                const int* __restrict__ row,
                                const float* __restrict__ wv,
                                const float* __restrict__ bv,
                                int j, float* __restrict__ v,
                                unsigned int* __restrict__ m, int n) {
    int e = blockIdx.x * blockDim.x + threadIdx.x;
    if (e >= n) return;
    float w = wv[j], b = bv[j];
    float z = raw[e] * w + b;
    float sig = 1.0f / (1.0f + expf(-z));
    float val = expf(sig);               // edge_logit = exp(sigmoid(raw*w+b)), in (1, e)
    v[e] = val;
    // positive floats: IEEE order == unsigned order; m pre-zeroed (0 < any val)
    atomicMax(&m[row[e]], __float_as_uint(val));
}

__global__ void edge_expsum_kernel(float* __restrict__ v,
                                   const int* __restrict__ row,
                                   const unsigned int* __restrict__ m,
                                   float* __restrict__ s, int n) {
    int e = blockIdx.x * blockDim.x + threadIdx.x;
    if (e >= n) return;
    int r = row[e];
    float val = expf(v[e] - __uint_as_float(m[r]));
    v[e] = val;
    atomicAdd(&s[r], val);
}

__global__ void edge_div_kernel(float* __restrict__ v,
                                const int* __restrict__ row,
                                const float* __restrict__ s, int n) {
    int e = blockIdx.x * blockDim.x + threadIdx.x;
    if (e >= n) return;
    v[e] = v[e] / (s[row[e]] + 1e-12f);
}

// ---------------- SpMM: out[row[e]] += att[e] * x[col[e]], one wave per edge ----------------

__global__ void spmm_kernel(const float* __restrict__ att,
                            const int* __restrict__ row,
                            const int* __restrict__ col,
                            const float* __restrict__ x,
                            float* __restrict__ out, int n) {
    int e = blockIdx.x * (blockDim.x >> 6) + (threadIdx.x >> 6);
    int lane = threadIdx.x & 63;
    if (e >= n) return;
    int r = row[e], c = col[e];
    float a = att[e];
    atomicAdd(&out[(size_t)r * DIM + lane], a * x[(size_t)c * DIM + lane]);
}

// ---------------- per-row attention layers ----------------

__device__ __forceinline__ float wave_sum(float x) {
    #pragma unroll
    for (int off = 32; off > 0; off >>= 1) x += __shfl_xor(x, off, 64);
    return x;
}

__device__ __forceinline__ float att_scalar(float dot, float b1, float w2, float b2, float addc) {
    float h = tanhf(dot + b1);
    float z = h * w2 + b2;
    float lr = z > 0.0f ? z : 0.2f * z;   // leaky_relu alpha=0.2
    return expf(lr) + addc;
}

__global__ void user_layer_kernel(const float* __restrict__ u,
                                  const float* __restrict__ ufi,
                                  const float* __restrict__ ufu,
                                  const float* __restrict__ W1,
                                  const float* __restrict__ b1,
                                  const float* __restrict__ w2,
                                  const float* __restrict__ b2,
                                  int k, float* __restrict__ out, int n) {
    int r = blockIdx.x * (blockDim.x >> 6) + (threadIdx.x >> 6);
    int lane = threadIdx.x & 63;
    if (r >= n) return;
    size_t idx = (size_t)r * DIM + lane;
    float uv = u[idx], fi = ufi[idx], fu = ufu[idx];
    const float* Wa = W1 + k * 2 * DIM;
    const float* Wb = W1 + (k + 1) * 2 * DIM;
    float d1 = uv * Wa[lane] + fi * Wa[DIM + lane];
    float d2 = uv * Wb[lane] + fu * Wb[DIM + lane];
    d1 = wave_sum(d1);
    d2 = wave_sum(d2);
    float a_int = att_scalar(d1, b1[k], w2[k], b2[k], 0.7f);
    float a_soc = att_scalar(d2, b1[k + 1], w2[k + 1], b2[k + 1], 0.3f);
    float s = a_int + a_soc;
    out[idx] = 0.5f * uv + 0.5f * ((a_int / s) * fi + (a_soc / s) * fu);
}

__global__ void item_layer_kernel(const float* __restrict__ it,
                                  const float* __restrict__ ifu,
                                  const float* __restrict__ W1,
                                  const float* __restrict__ b1,
                                  const float* __restrict__ w2,
                                  const float* __restrict__ b2,
                                  int k, float* __restrict__ out, int n) {
    int r = blockIdx.x * (blockDim.x >> 6) + (threadIdx.x >> 6);
    int lane = threadIdx.x & 63;
    if (r >= n) return;
    size_t idx = (size_t)r * DIM + lane;
    float iv = it[idx], fu = ifu[idx];
    const float* Wa = W1 + k * 2 * DIM;
    const float* Wb = W1 + (k + 1) * 2 * DIM;
    float d1 = iv * (Wa[lane] + Wa[DIM + lane]);   // concat([it, it])
    float d2 = iv * Wb[lane] + fu * Wb[DIM + lane];
    d1 = wave_sum(d1);
    d2 = wave_sum(d2);
    float a_self = att_scalar(d1, b1[k], w2[k], b2[k], 1.0f);
    float a_cust = att_scalar(d2, b1[k + 1], w2[k + 1], b2[k + 1], 1.0f);
    float s = a_self + a_cust;
    out[idx] = (a_self / s) * iv + (a_cust / s) * fu;
}

// ---------------- final: sigmoid(sum over 3D dims of fu[uidx]*fi[iidx]) ----------------

__global__ void final_kernel(const float* __restrict__ u0,
                             const float* __restrict__ u1,
                             const float* __restrict__ u2,
                             const float* __restrict__ i0,
                             const float* __restrict__ i1,
                             const float* __restrict__ i2,
                             const int* __restrict__ uidx,
                             const int* __restrict__ iidx,
                             float* __restrict__ out, int n) {
    int bb = blockIdx.x * (blockDim.x >> 6) + (threadIdx.x >> 6);
    int lane = threadIdx.x & 63;
    if (bb >= n) return;
    size_t ur = (size_t)uidx[bb] * DIM + lane;
    size_t ir = (size_t)iidx[bb] * DIM + lane;
    float acc = u0[ur] * i0[ir] + u1[ur] * i1[ir] + u2[ur] * i2[ir];
    acc = wave_sum(acc);
    if (lane == 0) out[bb] = 1.0f / (1.0f + expf(-acc));
}

// ---------------- launch ----------------

extern "C" void kernel_launch(void* const* d_in, const int* in_sizes, int n_in,
                              void* d_out, int out_size, void* d_ws, size_t ws_size,
                              hipStream_t stream) {
    const float* user_emb = (const float*)d_in[0];
    const float* item_emb = (const float*)d_in[1];
    const float* snii1 = (const float*)d_in[2];
    const float* snii2 = (const float*)d_in[3];
    const float* ciii1 = (const float*)d_in[4];
    const float* ciii2 = (const float*)d_in[5];
    const float* icii1 = (const float*)d_in[6];
    const float* icii2 = (const float*)d_in[7];
    const float* low_w = (const float*)d_in[8];
    const float* low_b = (const float*)d_in[9];
    const float* att1_W = (const float*)d_in[10];
    const float* att1_b = (const float*)d_in[11];
    const float* att2_w = (const float*)d_in[12];
    const float* att2_b = (const float*)d_in[13];
    const int* sn_row = (const int*)d_in[14];
    const int* sn_col = (const int*)d_in[15];
    const int* ci_row = (const int*)d_in[16];
    const int* ci_col = (const int*)d_in[17];
    const int* ic_row = (const int*)d_in[18];
    const int* ic_col = (const int*)d_in[19];
    const int* user_idx = (const int*)d_in[20];
    const int* item_idx = (const int*)d_in[21];
    float* out = (float*)d_out;

    const int Es  = in_sizes[2];
    const int Eui = in_sizes[4];
    const int Eiu = in_sizes[6];
    const int U = in_sizes[0] / DIM;
    const int I = in_sizes[1] / DIM;
    const int B = in_sizes[20];

    float* ws = (float*)d_ws;
    size_t off = 0;
    float* att_sn1 = ws + off; off += Es;
    float* att_sn2 = ws + off; off += Es;
    float* att_ci1 = ws + off; off += Eui;
    float* att_ci2 = ws + off; off += Eui;
    float* att_ic1 = ws + off; off += Eiu;
    float* att_ic2 = ws + off; off += Eiu;
    float* m_buf   = ws + off; off += U;            // segment max (uint-cast floats)
    float* s_buf   = ws + off; off += U;            // segment sum (adjacent to m_buf)
    float* ufi = ws + off; off += (size_t)U * DIM;  // u_from_i
    float* ufu = ws + off; off += (size_t)U * DIM;  // u_from_u (adjacent to ufi)
    float* ifu = ws + off; off += (size_t)I * DIM;  // i_from_u
    float* u1  = ws + off; off += (size_t)U * DIM;
    float* u2  = ws + off; off += (size_t)U * DIM;
    float* i1  = ws + off; off += (size_t)I * DIM;
    float* i2  = ws + off; off += (size_t)I * DIM;
    // total ~41M floats (~164 MB) <= ws_size (assumed)

    auto softmax_set = [&](const float* raw, const int* rows, int j, int n, float* att) {
        hipMemsetAsync(m_buf, 0, 2 * (size_t)U * sizeof(float), stream);  // zeros m_buf + s_buf
        int blocks = (n + 255) / 256;
        edge_max_kernel<<<blocks, 256, 0, stream>>>(raw, rows, low_w, low_b, j, att,
                                                    (unsigned int*)m_buf, n);
        edge_expsum_kernel<<<blocks, 256, 0, stream>>>(att, rows, (const unsigned int*)m_buf,
                                                       s_buf, n);
        edge_div_kernel<<<blocks, 256, 0, stream>>>(att, rows, s_buf, n);
    };

    auto spmm = [&](const float* att, const int* rows, const int* cols,
                    const float* x, float* o, int n) {
        spmm_kernel<<<(n + 3) / 4, 256, 0, stream>>>(att, rows, cols, x, o, n);
    };

    // low-level edge attention (sparse row softmax), 6 sets
    softmax_set(snii1, sn_row, 0, Es,  att_sn1);
    softmax_set(snii2, sn_row, 1, Es,  att_sn2);
    softmax_set(ciii1, ci_row, 2, Eui, att_ci1);
    softmax_set(ciii2, ci_row, 3, Eui, att_ci2);
    softmax_set(icii1, ic_row, 4, Eiu, att_ic1);
    softmax_set(icii2, ic_row, 5, Eiu, att_ic2);

    // layer 1: u1 = user_layer(u0, i0, sn1, ci1, k=0)
    hipMemsetAsync(ufi, 0, 2 * (size_t)U * DIM * sizeof(float), stream);  // zeros ufi + ufu
    spmm(att_ci1, ci_row, ci_col, item_emb, ufi, Eui);
    spmm(att_sn1, sn_row, sn_col, user_emb, ufu, Es);
    user_layer_kernel<<<(U + 3) / 4, 256, 0, stream>>>(user_emb, ufi, ufu,
        att1_W, att1_b, att2_w, att2_b, 0, u1, U);

    // layer 1: i1 = item_layer(u0, i0, ic1, k=4)
    hipMemsetAsync(ifu, 0, (size_t)I * DIM * sizeof(float), stream);
    spmm(att_ic1, ic_row, ic_col, user_emb, ifu, Eiu);
    item_layer_kernel<<<(I + 3) / 4, 256, 0, stream>>>(item_emb, ifu,
        att1_W, att1_b, att2_w, att2_b, 4, i1, I);

    // layer 2: u2 = user_layer(u1, i1, sn2, ci2, k=2)
    hipMemsetAsync(ufi, 0, 2 * (size_t)U * DIM * sizeof(float), stream);
    spmm(att_ci2, ci_row, ci_col, i1, ufi, Eui);
    spmm(att_sn2, sn_row, sn_col, u1, ufu, Es);
    user_layer_kernel<<<(U + 3) / 4, 256, 0, stream>>>(u1, ufi, ufu,
        att1_W, att1_b, att2_w, att2_b, 2, u2, U);

    // layer 2: i2 = item_layer(u1, i1, ic2, k=6)
    hipMemsetAsync(ifu, 0, (size_t)I * DIM * sizeof(float), stream);
    spmm(att_ic2, ic_row, ic_col, u1, ifu, Eiu);
    item_layer_kernel<<<(I + 3) / 4, 256, 0, stream>>>(i1, ifu,
        att1_W, att1_b, att2_w, att2_b, 6, i2, I);

    // final gather-dot-sigmoid
    final_kernel<<<(B + 3) / 4, 256, 0, stream>>>(user_emb, u1, u2, item_emb, i1, i2,
                                                  user_idx, item_idx, out, B);
}

// Round 2
// 965.528 us; speedup vs baseline: 2.1348x; 2.1348x over previous
//
#include <hip/hip_runtime.h>
#include <math.h>

#define DIM 64
#define SCAN_B 256
#define SCAN2_B 512

// ---------------- CSR build ----------------

__global__ void hist_kernel(const int* __restrict__ row, int* __restrict__ cnt, int n) {
    int e = blockIdx.x * blockDim.x + threadIdx.x;
    if (e < n) atomicAdd(&cnt[row[e]], 1);
}

// per-block exclusive scan; writes exclusive-within-block to ptr, block total to bsum
__global__ void scan1_kernel(const int* __restrict__ cnt, int* __restrict__ ptr,
                             int* __restrict__ bsum, int n) {
    __shared__ int sm[SCAN_B];
    int i = blockIdx.x * SCAN_B + threadIdx.x;
    int v = (i < n) ? cnt[i] : 0;
    sm[threadIdx.x] = v;
    __syncthreads();
    for (int off = 1; off < SCAN_B; off <<= 1) {
        int t = 0;
        if ((int)threadIdx.x >= off) t = sm[threadIdx.x - off];
        __syncthreads();
        if ((int)threadIdx.x >= off) sm[threadIdx.x] += t;
        __syncthreads();
    }
    if (i < n) ptr[i] = sm[threadIdx.x] - v;               // exclusive within block
    if (threadIdx.x == SCAN_B - 1) bsum[blockIdx.x] = sm[threadIdx.x];
}

// single-block exclusive scan of block sums (nb <= SCAN2_B)
__global__ void scan2_kernel(int* __restrict__ bsum, int nb) {
    __shared__ int sm[SCAN2_B];
    int i = threadIdx.x;
    int v = (i < nb) ? bsum[i] : 0;
    sm[i] = v;
    __syncthreads();
    for (int off = 1; off < SCAN2_B; off <<= 1) {
        int t = 0;
        if (i >= off) t = sm[i - off];
        __syncthreads();
        if (i >= off) sm[i] += t;
        __syncthreads();
    }
    if (i < nb) bsum[i] = sm[i] - v;                       // exclusive
}

__global__ void scan3_kernel(int* __restrict__ ptr, const int* __restrict__ bsum,
                             int n, int total) {
    int i = blockIdx.x * SCAN_B + threadIdx.x;
    if (i < n) {
        ptr[i] += bsum[blockIdx.x];
        if (i == n - 1) ptr[n] = total;
    }
}

__global__ void scatter_kernel(const int* __restrict__ row, const int* __restrict__ col,
                               const int* __restrict__ ptr, int* __restrict__ cnt,
                               int* __restrict__ col_csr, int* __restrict__ eid_csr, int n) {
    int e = blockIdx.x * blockDim.x + threadIdx.x;
    if (e >= n) return;
    int r = row[e];
    int pos = ptr[r] + atomicAdd(&cnt[r], 1);
    col_csr[pos] = col[e];
    eid_csr[pos] = e;
}

// ---------------- row-local sparse softmax (two edge-value sets sharing one CSR) ----------------

__global__ void softmax_csr_kernel(const float* __restrict__ raw1, const float* __restrict__ raw2,
                                   const int* __restrict__ ptr, const int* __restrict__ eid,
                                   const float* __restrict__ lw, const float* __restrict__ lb,
                                   int j1, int j2,
                                   float* __restrict__ att1, float* __restrict__ att2, int nrows) {
    int r = blockIdx.x * blockDim.x + threadIdx.x;
    if (r >= nrows) return;
    int s0 = ptr[r], s1 = ptr[r + 1];
    float w1 = lw[j1], b1 = lb[j1], w2 = lw[j2], b2 = lb[j2];
    float m1 = -1e30f, m2 = -1e30f;
    for (int e = s0; e < s1; e++) {
        int id = eid[e];
        float v1 = expf(1.0f / (1.0f + expf(-(raw1[id] * w1 + b1))));
        float v2 = expf(1.0f / (1.0f + expf(-(raw2[id] * w2 + b2))));
        att1[e] = v1; att2[e] = v2;
        m1 = fmaxf(m1, v1); m2 = fmaxf(m2, v2);
    }
    float sum1 = 0.0f, sum2 = 0.0f;
    for (int e = s0; e < s1; e++) {
        float e1 = expf(att1[e] - m1), e2 = expf(att2[e] - m2);
        att1[e] = e1; att2[e] = e2;
        sum1 += e1; sum2 += e2;
    }
    float r1 = 1.0f / (sum1 + 1e-12f), r2 = 1.0f / (sum2 + 1e-12f);
    for (int e = s0; e < s1; e++) { att1[e] *= r1; att2[e] *= r2; }
}

// ---------------- fused gather-SpMM + attention-gated mix (one wave per row) ----------------

__device__ __forceinline__ float wave_sum(float x) {
    #pragma unroll
    for (int off = 32; off > 0; off >>= 1) x += __shfl_xor(x, off, 64);
    return x;
}

__device__ __forceinline__ float att_scalar(float dot, float b1, float w2, float b2, float addc) {
    float h = tanhf(dot + b1);
    float z = h * w2 + b2;
    float lr = z > 0.0f ? z : 0.2f * z;   // leaky_relu alpha=0.2
    return expf(lr) + addc;
}

__global__ void user_layer_fused(const float* __restrict__ u, const float* __restrict__ it,
                                 const int* __restrict__ ci_ptr, const int* __restrict__ ci_col,
                                 const float* __restrict__ att_ci,
                                 const int* __restrict__ sn_ptr, const int* __restrict__ sn_col,
                                 const float* __restrict__ att_sn,
                                 const float* __restrict__ W1, const float* __restrict__ b1v,
                                 const float* __restrict__ w2v, const float* __restrict__ b2v,
                                 int k, float* __restrict__ out, int nrows,
                                 const int* __restrict__ rowsel) {
    int b = blockIdx.x * (blockDim.x >> 6) + (threadIdx.x >> 6);
    int lane = threadIdx.x & 63;
    if (b >= nrows) return;
    int r = rowsel ? rowsel[b] : b;
    float acc_i = 0.0f, acc_u = 0.0f;
    int e0 = ci_ptr[r], e1 = ci_ptr[r + 1];
    for (int e = e0; e < e1; e++)
        acc_i += att_ci[e] * it[(size_t)ci_col[e] * DIM + lane];
    e0 = sn_ptr[r]; e1 = sn_ptr[r + 1];
    for (int e = e0; e < e1; e++)
        acc_u += att_sn[e] * u[(size_t)sn_col[e] * DIM + lane];
    float uv = u[(size_t)r * DIM + lane];
    const float* Wa = W1 + k * 2 * DIM;
    const float* Wb = Wa + 2 * DIM;
    float d1 = uv * Wa[lane] + acc_i * Wa[DIM + lane];
    float d2 = uv * Wb[lane] + acc_u * Wb[DIM + lane];
    d1 = wave_sum(d1);
    d2 = wave_sum(d2);
    float a_int = att_scalar(d1, b1v[k], w2v[k], b2v[k], 0.7f);
    float a_soc = att_scalar(d2, b1v[k + 1], w2v[k + 1], b2v[k + 1], 0.3f);
    float s = a_int + a_soc;
    out[(size_t)b * DIM + lane] = 0.5f * uv + 0.5f * ((a_int / s) * acc_i + (a_soc / s) * acc_u);
}

__global__ void item_layer_fused(const float* __restrict__ it, const float* __restrict__ u,
                                 const int* __restrict__ ic_ptr, const int* __restrict__ ic_col,
                                 const float* __restrict__ att_ic,
                                 const float* __restrict__ W1, const float* __restrict__ b1v,
                                 const float* __restrict__ w2v, const float* __restrict__ b2v,
                                 int k, float* __restrict__ out, int nrows,
                                 const int* __restrict__ rowsel) {
    int b = blockIdx.x * (blockDim.x >> 6) + (threadIdx.x >> 6);
    int lane = threadIdx.x & 63;
    if (b >= nrows) return;
    int r = rowsel ? rowsel[b] : b;
    float acc_u = 0.0f;
    int e0 = ic_ptr[r], e1 = ic_ptr[r + 1];
    for (int e = e0; e < e1; e++)
        acc_u += att_ic[e] * u[(size_t)ic_col[e] * DIM + lane];
    float iv = it[(size_t)r * DIM + lane];
    const float* Wa = W1 + k * 2 * DIM;
    const float* Wb = Wa + 2 * DIM;
    float d1 = iv * (Wa[lane] + Wa[DIM + lane]);   // concat([it, it])
    float d2 = iv * Wb[lane] + acc_u * Wb[DIM + lane];
    d1 = wave_sum(d1);
    d2 = wave_sum(d2);
    float a_self = att_scalar(d1, b1v[k], w2v[k], b2v[k], 1.0f);
    float a_cust = att_scalar(d2, b1v[k + 1], w2v[k + 1], b2v[k + 1], 1.0f);
    float s = a_self + a_cust;
    out[(size_t)b * DIM + lane] = (a_self / s) * iv + (a_cust / s) * acc_u;
}

// ---------------- final: sigmoid(dot over [u0|u1|u2] . [i0|i1|i2]) ----------------

__global__ void final_kernel(const float* __restrict__ u0, const float* __restrict__ u1,
                             const float* __restrict__ u2s,
                             const float* __restrict__ i0, const float* __restrict__ i1,
                             const float* __restrict__ i2s,
                             const int* __restrict__ uidx, const int* __restrict__ iidx,
                             float* __restrict__ out, int n) {
    int b = blockIdx.x * (blockDim.x >> 6) + (threadIdx.x >> 6);
    int lane = threadIdx.x & 63;
    if (b >= n) return;
    size_t ur = (size_t)uidx[b] * DIM + lane;
    size_t ir = (size_t)iidx[b] * DIM + lane;
    size_t sr = (size_t)b * DIM + lane;
    float acc = u0[ur] * i0[ir] + u1[ur] * i1[ir] + u2s[sr] * i2s[sr];
    acc = wave_sum(acc);
    if (lane == 0) out[b] = 1.0f / (1.0f + expf(-acc));
}

// ---------------- launch ----------------

extern "C" void kernel_launch(void* const* d_in, const int* in_sizes, int n_in,
                              void* d_out, int out_size, void* d_ws, size_t ws_size,
                              hipStream_t stream) {
    const float* user_emb = (const float*)d_in[0];
    const float* item_emb = (const float*)d_in[1];
    const float* snii1 = (const float*)d_in[2];
    const float* snii2 = (const float*)d_in[3];
    const float* ciii1 = (const float*)d_in[4];
    const float* ciii2 = (const float*)d_in[5];
    const float* icii1 = (const float*)d_in[6];
    const float* icii2 = (const float*)d_in[7];
    const float* low_w = (const float*)d_in[8];
    const float* low_b = (const float*)d_in[9];
    const float* att1_W = (const float*)d_in[10];
    const float* att1_b = (const float*)d_in[11];
    const float* att2_w = (const float*)d_in[12];
    const float* att2_b = (const float*)d_in[13];
    const int* sn_row = (const int*)d_in[14];
    const int* sn_col = (const int*)d_in[15];
    const int* ci_row = (const int*)d_in[16];
    const int* ci_col = (const int*)d_in[17];
    const int* ic_row = (const int*)d_in[18];
    const int* ic_col = (const int*)d_in[19];
    const int* user_idx = (const int*)d_in[20];
    const int* item_idx = (const int*)d_in[21];
    float* out = (float*)d_out;

    const int Es  = in_sizes[2];
    const int Eui = in_sizes[4];
    const int Eiu = in_sizes[6];
    const int U = in_sizes[0] / DIM;
    const int I = in_sizes[1] / DIM;
    const int B = in_sizes[20];

    // ---- workspace carve (all 4-byte units) ----
    char* wsb = (char*)d_ws;
    size_t off = 0;
    auto alloc = [&](size_t n_units) { void* p = wsb + off * 4; off += n_units; return p; };

    int* sn_ptr = (int*)alloc(U + 1);
    int* ci_ptr = (int*)alloc(U + 1);
    int* ic_ptr = (int*)alloc(I + 1);
    int* cnt    = (int*)alloc(U);            // reused per set (U >= I)
    int* bsum   = (int*)alloc(SCAN2_B);
    int* sn_colc = (int*)alloc(Es);
    int* sn_eid  = (int*)alloc(Es);
    int* ci_colc = (int*)alloc(Eui);
    int* ci_eid  = (int*)alloc(Eui);
    int* ic_colc = (int*)alloc(Eiu);
    int* ic_eid  = (int*)alloc(Eiu);
    float* att_sn1 = (float*)alloc(Es);
    float* att_sn2 = (float*)alloc(Es);
    float* att_ci1 = (float*)alloc(Eui);
    float* att_ci2 = (float*)alloc(Eui);
    float* att_ic1 = (float*)alloc(Eiu);
    float* att_ic2 = (float*)alloc(Eiu);
    float* u1  = (float*)alloc((size_t)U * DIM);
    float* i1  = (float*)alloc((size_t)I * DIM);
    float* u2s = (float*)alloc((size_t)B * DIM);
    float* i2s = (float*)alloc((size_t)B * DIM);
    (void)ws_size;

    // ---- CSR build for one edge set ----
    auto build_csr = [&](const int* rows, const int* cols, int n_edges, int n_rows,
                         int* ptr, int* colc, int* eidc) {
        int eb = (n_edges + 255) / 256;
        int nb = (n_rows + SCAN_B - 1) / SCAN_B;
        hipMemsetAsync(cnt, 0, (size_t)n_rows * sizeof(int), stream);
        hist_kernel<<<eb, 256, 0, stream>>>(rows, cnt, n_edges);
        scan1_kernel<<<nb, SCAN_B, 0, stream>>>(cnt, ptr, bsum, n_rows);
        scan2_kernel<<<1, SCAN2_B, 0, stream>>>(bsum, nb);
        scan3_kernel<<<nb, SCAN_B, 0, stream>>>(ptr, bsum, n_rows, n_edges);
        hipMemsetAsync(cnt, 0, (size_t)n_rows * sizeof(int), stream);
        scatter_kernel<<<eb, 256, 0, stream>>>(rows, cols, ptr, cnt, colc, eidc, n_edges);
    };

    build_csr(sn_row, sn_col, Es,  U, sn_ptr, sn_colc, sn_eid);
    build_csr(ci_row, ci_col, Eui, U, ci_ptr, ci_colc, ci_eid);
    build_csr(ic_row, ic_col, Eiu, I, ic_ptr, ic_colc, ic_eid);

    // ---- row-local softmaxes (paired sets per CSR) ----
    softmax_csr_kernel<<<(U + 255) / 256, 256, 0, stream>>>(snii1, snii2, sn_ptr, sn_eid,
        low_w, low_b, 0, 1, att_sn1, att_sn2, U);
    softmax_csr_kernel<<<(U + 255) / 256, 256, 0, stream>>>(ciii1, ciii2, ci_ptr, ci_eid,
        low_w, low_b, 2, 3, att_ci1, att_ci2, U);
    softmax_csr_kernel<<<(I + 255) / 256, 256, 0, stream>>>(icii1, icii2, ic_ptr, ic_eid,
        low_w, low_b, 4, 5, att_ic1, att_ic2, I);

    // ---- layer 1 (full) ----
    user_layer_fused<<<(U + 3) / 4, 256, 0, stream>>>(user_emb, item_emb,
        ci_ptr, ci_colc, att_ci1, sn_ptr, sn_colc, att_sn1,
        att1_W, att1_b, att2_w, att2_b, 0, u1, U, nullptr);
    item_layer_fused<<<(I + 3) / 4, 256, 0, stream>>>(item_emb, user_emb,
        ic_ptr, ic_colc, att_ic1,
        att1_W, att1_b, att2_w, att2_b, 4, i1, I, nullptr);

    // ---- layer 2 (only at sampled rows) ----
    user_layer_fused<<<(B + 3) / 4, 256, 0, stream>>>(u1, i1,
        ci_ptr, ci_colc, att_ci2, sn_ptr, sn_colc, att_sn2,
        att1_W, att1_b, att2_w, att2_b, 2, u2s, B, user_idx);
    item_layer_fused<<<(B + 3) / 4, 256, 0, stream>>>(i1, u1,
        ic_ptr, ic_colc, att_ic2,
        att1_W, att1_b, att2_w, att2_b, 6, i2s, B, item_idx);

    // ---- final gather-dot-sigmoid ----
    final_kernel<<<(B + 3) / 4, 256, 0, stream>>>(user_emb, u1, u2s, item_emb, i1, i2s,
                                                  user_idx, item_idx, out, B);
}

// Round 3
// 754.395 us; speedup vs baseline: 2.7323x; 1.2799x over previous
//
#include <hip/hip_runtime.h>
#include <math.h>

#define DIM 64
#define SCAN_B 256
#define SCAN2_B 512

// ---------------- CSR build ----------------

__global__ void hist_kernel(const int* __restrict__ row, int* __restrict__ cnt, int n) {
    int e = blockIdx.x * blockDim.x + threadIdx.x;
    if (e < n) atomicAdd(&cnt[row[e]], 1);
}

__global__ void scan1_kernel(const int* __restrict__ cnt, int* __restrict__ ptr,
                             int* __restrict__ bsum, int n) {
    __shared__ int sm[SCAN_B];
    int i = blockIdx.x * SCAN_B + threadIdx.x;
    int v = (i < n) ? cnt[i] : 0;
    sm[threadIdx.x] = v;
    __syncthreads();
    for (int off = 1; off < SCAN_B; off <<= 1) {
        int t = 0;
        if ((int)threadIdx.x >= off) t = sm[threadIdx.x - off];
        __syncthreads();
        if ((int)threadIdx.x >= off) sm[threadIdx.x] += t;
        __syncthreads();
    }
    if (i < n) ptr[i] = sm[threadIdx.x] - v;
    if (threadIdx.x == SCAN_B - 1) bsum[blockIdx.x] = sm[threadIdx.x];
}

__global__ void scan2_kernel(int* __restrict__ bsum, int nb) {
    __shared__ int sm[SCAN2_B];
    int i = threadIdx.x;
    int v = (i < nb) ? bsum[i] : 0;
    sm[i] = v;
    __syncthreads();
    for (int off = 1; off < SCAN2_B; off <<= 1) {
        int t = 0;
        if (i >= off) t = sm[i - off];
        __syncthreads();
        if (i >= off) sm[i] += t;
        __syncthreads();
    }
    if (i < nb) bsum[i] = sm[i] - v;
}

__global__ void scan3_kernel(int* __restrict__ ptr, const int* __restrict__ bsum,
                             int n, int total) {
    int i = blockIdx.x * SCAN_B + threadIdx.x;
    if (i < n) {
        ptr[i] += bsum[blockIdx.x];
        if (i == n - 1) ptr[n] = total;
    }
}

// scatter edges into CSR order; fuse edge_logit: v = exp(sigmoid(raw*w+b))
__global__ void scatter_fused(const int* __restrict__ row, const int* __restrict__ col,
                              const float* __restrict__ raw1, const float* __restrict__ raw2,
                              const float* __restrict__ lw, const float* __restrict__ lb,
                              int j1, int j2,
                              const int* __restrict__ ptr, int* __restrict__ cnt,
                              int* __restrict__ colc, float* __restrict__ v1,
                              float* __restrict__ v2, int n) {
    int e = blockIdx.x * blockDim.x + threadIdx.x;
    if (e >= n) return;
    int r = row[e];
    int pos = ptr[r] + atomicAdd(&cnt[r], 1);
    colc[pos] = col[e];
    float w1 = lw[j1], b1 = lb[j1], w2 = lw[j2], b2 = lb[j2];
    v1[pos] = expf(1.0f / (1.0f + expf(-(raw1[e] * w1 + b1))));
    v2[pos] = expf(1.0f / (1.0f + expf(-(raw2[e] * w2 + b2))));
}

// ---------------- wave-per-row sparse softmax (pair of value sets) ----------------
// leaves att unnormalized-exp; stores reciprocal row sum (folded into layer accum)

__global__ void softmax_rows(float* __restrict__ att1, float* __restrict__ att2,
                             const int* __restrict__ ptr,
                             float* __restrict__ rs1, float* __restrict__ rs2, int nrows) {
    int r = blockIdx.x * (blockDim.x >> 6) + (threadIdx.x >> 6);
    int lane = threadIdx.x & 63;
    if (r >= nrows) return;
    int s0 = ptr[r], s1 = ptr[r + 1];
    float m1 = -1e30f, m2 = -1e30f;
    for (int e = s0 + lane; e < s1; e += 64) {
        m1 = fmaxf(m1, att1[e]);
        m2 = fmaxf(m2, att2[e]);
    }
    #pragma unroll
    for (int off = 32; off > 0; off >>= 1) {
        m1 = fmaxf(m1, __shfl_xor(m1, off, 64));
        m2 = fmaxf(m2, __shfl_xor(m2, off, 64));
    }
    float sum1 = 0.0f, sum2 = 0.0f;
    for (int e = s0 + lane; e < s1; e += 64) {
        float e1 = expf(att1[e] - m1); att1[e] = e1; sum1 += e1;
        float e2 = expf(att2[e] - m2); att2[e] = e2; sum2 += e2;
    }
    #pragma unroll
    for (int off = 32; off > 0; off >>= 1) {
        sum1 += __shfl_xor(sum1, off, 64);
        sum2 += __shfl_xor(sum2, off, 64);
    }
    if (lane == 0) {
        rs1[r] = 1.0f / (sum1 + 1e-12f);
        rs2[r] = 1.0f / (sum2 + 1e-12f);
    }
}

// ---------------- fused gather-SpMM + attention-gated mix ----------------
// one wave per row; 4 groups of 16 lanes, each group one edge at a time, float4/lane

__device__ __forceinline__ float att_scalar(float dot, float b1, float w2, float b2, float addc) {
    float h = tanhf(dot + b1);
    float z = h * w2 + b2;
    float lr = z > 0.0f ? z : 0.2f * z;   // leaky_relu alpha=0.2
    return expf(lr) + addc;
}

__device__ __forceinline__ void xgroup_reduce(float4& a) {
    #pragma unroll
    for (int off = 16; off < 64; off <<= 1) {
        a.x += __shfl_xor(a.x, off, 64);
        a.y += __shfl_xor(a.y, off, 64);
        a.z += __shfl_xor(a.z, off, 64);
        a.w += __shfl_xor(a.w, off, 64);
    }
}

__device__ __forceinline__ float dot16(float d) {
    #pragma unroll
    for (int off = 1; off < 16; off <<= 1) d += __shfl_xor(d, off, 64);
    return d;
}

__global__ void user_layer_fused(const float* __restrict__ u, const float* __restrict__ it,
                                 const int* __restrict__ ci_ptr, const int* __restrict__ ci_col,
                                 const float* __restrict__ att_ci, const float* __restrict__ rs_ci,
                                 const int* __restrict__ sn_ptr, const int* __restrict__ sn_col,
                                 const float* __restrict__ att_sn, const float* __restrict__ rs_sn,
                                 const float* __restrict__ W1, const float* __restrict__ b1v,
                                 const float* __restrict__ w2v, const float* __restrict__ b2v,
                                 int k, float* __restrict__ out, int nrows,
                                 const int* __restrict__ rowsel) {
    int wid = blockIdx.x * (blockDim.x >> 6) + (threadIdx.x >> 6);
    int lane = threadIdx.x & 63;
    if (wid >= nrows) return;
    int g = lane >> 4, l16 = lane & 15;
    int r = rowsel ? rowsel[wid] : wid;

    float4 ai = make_float4(0.f, 0.f, 0.f, 0.f);
    float4 au = make_float4(0.f, 0.f, 0.f, 0.f);
    int e0 = ci_ptr[r], e1 = ci_ptr[r + 1];
    for (int e = e0 + g; e < e1; e += 4) {
        float a = att_ci[e];
        int c = ci_col[e];
        float4 v = ((const float4*)(it + (size_t)c * DIM))[l16];
        ai.x += a * v.x; ai.y += a * v.y; ai.z += a * v.z; ai.w += a * v.w;
    }
    e0 = sn_ptr[r]; e1 = sn_ptr[r + 1];
    for (int e = e0 + g; e < e1; e += 4) {
        float a = att_sn[e];
        int c = sn_col[e];
        float4 v = ((const float4*)(u + (size_t)c * DIM))[l16];
        au.x += a * v.x; au.y += a * v.y; au.z += a * v.z; au.w += a * v.w;
    }
    xgroup_reduce(ai);
    xgroup_reduce(au);
    float ri = rs_ci[r], ru = rs_sn[r];
    ai.x *= ri; ai.y *= ri; ai.z *= ri; ai.w *= ri;
    au.x *= ru; au.y *= ru; au.z *= ru; au.w *= ru;

    float4 uv = ((const float4*)(u + (size_t)r * DIM))[l16];
    const float* Wa = W1 + k * 2 * DIM;
    const float* Wb = Wa + 2 * DIM;
    float4 wa0 = ((const float4*)Wa)[l16], wa1 = ((const float4*)(Wa + DIM))[l16];
    float4 wb0 = ((const float4*)Wb)[l16], wb1 = ((const float4*)(Wb + DIM))[l16];
    float d1 = uv.x * wa0.x + uv.y * wa0.y + uv.z * wa0.z + uv.w * wa0.w
             + ai.x * wa1.x + ai.y * wa1.y + ai.z * wa1.z + ai.w * wa1.w;
    float d2 = uv.x * wb0.x + uv.y * wb0.y + uv.z * wb0.z + uv.w * wb0.w
             + au.x * wb1.x + au.y * wb1.y + au.z * wb1.z + au.w * wb1.w;
    d1 = dot16(d1);
    d2 = dot16(d2);
    float a_int = att_scalar(d1, b1v[k], w2v[k], b2v[k], 0.7f);
    float a_soc = att_scalar(d2, b1v[k + 1], w2v[k + 1], b2v[k + 1], 0.3f);
    float s = a_int + a_soc;
    if (g == 0) {
        float4 o;
        o.x = 0.5f * uv.x + 0.5f * ((a_int / s) * ai.x + (a_soc / s) * au.x);
        o.y = 0.5f * uv.y + 0.5f * ((a_int / s) * ai.y + (a_soc / s) * au.y);
        o.z = 0.5f * uv.z + 0.5f * ((a_int / s) * ai.z + (a_soc / s) * au.z);
        o.w = 0.5f * uv.w + 0.5f * ((a_int / s) * ai.w + (a_soc / s) * au.w);
        ((float4*)(out + (size_t)wid * DIM))[l16] = o;
    }
}

__global__ void item_layer_fused(const float* __restrict__ it, const float* __restrict__ u,
                                 const int* __restrict__ ic_ptr, const int* __restrict__ ic_col,
                                 const float* __restrict__ att_ic, const float* __restrict__ rs_ic,
                                 const float* __restrict__ W1, const float* __restrict__ b1v,
                                 const float* __restrict__ w2v, const float* __restrict__ b2v,
                                 int k, float* __restrict__ out, int nrows,
                                 const int* __restrict__ rowsel) {
    int wid = blockIdx.x * (blockDim.x >> 6) + (threadIdx.x >> 6);
    int lane = threadIdx.x & 63;
    if (wid >= nrows) return;
    int g = lane >> 4, l16 = lane & 15;
    int r = rowsel ? rowsel[wid] : wid;

    float4 au = make_float4(0.f, 0.f, 0.f, 0.f);
    int e0 = ic_ptr[r], e1 = ic_ptr[r + 1];
    for (int e = e0 + g; e < e1; e += 4) {
        float a = att_ic[e];
        int c = ic_col[e];
        float4 v = ((const float4*)(u + (size_t)c * DIM))[l16];
        au.x += a * v.x; au.y += a * v.y; au.z += a * v.z; au.w += a * v.w;
    }
    xgroup_reduce(au);
    float ru = rs_ic[r];
    au.x *= ru; au.y *= ru; au.z *= ru; au.w *= ru;

    float4 iv = ((const float4*)(it + (size_t)r * DIM))[l16];
    const float* Wa = W1 + k * 2 * DIM;
    const float* Wb = Wa + 2 * DIM;
    float4 wa0 = ((const float4*)Wa)[l16], wa1 = ((const float4*)(Wa + DIM))[l16];
    float4 wb0 = ((const float4*)Wb)[l16], wb1 = ((const float4*)(Wb + DIM))[l16];
    float d1 = iv.x * (wa0.x + wa1.x) + iv.y * (wa0.y + wa1.y)
             + iv.z * (wa0.z + wa1.z) + iv.w * (wa0.w + wa1.w);   // concat([it,it])
    float d2 = iv.x * wb0.x + iv.y * wb0.y + iv.z * wb0.z + iv.w * wb0.w
             + au.x * wb1.x + au.y * wb1.y + au.z * wb1.z + au.w * wb1.w;
    d1 = dot16(d1);
    d2 = dot16(d2);
    float a_self = att_scalar(d1, b1v[k], w2v[k], b2v[k], 1.0f);
    float a_cust = att_scalar(d2, b1v[k + 1], w2v[k + 1], b2v[k + 1], 1.0f);
    float s = a_self + a_cust;
    if (g == 0) {
        float4 o;
        o.x = (a_self / s) * iv.x + (a_cust / s) * au.x;
        o.y = (a_self / s) * iv.y + (a_cust / s) * au.y;
        o.z = (a_self / s) * iv.z + (a_cust / s) * au.z;
        o.w = (a_self / s) * iv.w + (a_cust / s) * au.w;
        ((float4*)(out + (size_t)wid * DIM))[l16] = o;
    }
}

// ---------------- final: sigmoid(dot over [u0|u1|u2] . [i0|i1|i2]) ----------------

__global__ void final_kernel(const float* __restrict__ u0, const float* __restrict__ u1,
                             const float* __restrict__ u2s,
                             const float* __restrict__ i0, const float* __restrict__ i1,
                             const float* __restrict__ i2s,
                             const int* __restrict__ uidx, const int* __restrict__ iidx,
                             float* __restrict__ out, int n) {
    int b = blockIdx.x * (blockDim.x >> 6) + (threadIdx.x >> 6);
    int lane = threadIdx.x & 63;
    if (b >= n) return;
    size_t ur = (size_t)uidx[b] * DIM + lane;
    size_t ir = (size_t)iidx[b] * DIM + lane;
    size_t sr = (size_t)b * DIM + lane;
    float acc = u0[ur] * i0[ir] + u1[ur] * i1[ir] + u2s[sr] * i2s[sr];
    #pragma unroll
    for (int off = 32; off > 0; off >>= 1) acc += __shfl_xor(acc, off, 64);
    if (lane == 0) out[b] = 1.0f / (1.0f + expf(-acc));
}

// ---------------- launch ----------------

extern "C" void kernel_launch(void* const* d_in, const int* in_sizes, int n_in,
                              void* d_out, int out_size, void* d_ws, size_t ws_size,
                              hipStream_t stream) {
    const float* user_emb = (const float*)d_in[0];
    const float* item_emb = (const float*)d_in[1];
    const float* snii1 = (const float*)d_in[2];
    const float* snii2 = (const float*)d_in[3];
    const float* ciii1 = (const float*)d_in[4];
    const float* ciii2 = (const float*)d_in[5];
    const float* icii1 = (const float*)d_in[6];
    const float* icii2 = (const float*)d_in[7];
    const float* low_w = (const float*)d_in[8];
    const float* low_b = (const float*)d_in[9];
    const float* att1_W = (const float*)d_in[10];
    const float* att1_b = (const float*)d_in[11];
    const float* att2_w = (const float*)d_in[12];
    const float* att2_b = (const float*)d_in[13];
    const int* sn_row = (const int*)d_in[14];
    const int* sn_col = (const int*)d_in[15];
    const int* ci_row = (const int*)d_in[16];
    const int* ci_col = (const int*)d_in[17];
    const int* ic_row = (const int*)d_in[18];
    const int* ic_col = (const int*)d_in[19];
    const int* user_idx = (const int*)d_in[20];
    const int* item_idx = (const int*)d_in[21];
    float* out = (float*)d_out;

    const int Es  = in_sizes[2];
    const int Eui = in_sizes[4];
    const int Eiu = in_sizes[6];
    const int U = in_sizes[0] / DIM;
    const int I = in_sizes[1] / DIM;
    const int B = in_sizes[20];

    // ---- workspace carve (4-byte units, 16B-aligned blocks for float4 access) ----
    char* wsb = (char*)d_ws;
    size_t off = 0;
    auto alloc = [&](size_t n_units) {
        off = (off + 3) & ~(size_t)3;          // 16-byte align
        void* p = wsb + off * 4; off += n_units; return p;
    };

    int* sn_ptr = (int*)alloc(U + 1);
    int* ci_ptr = (int*)alloc(U + 1);
    int* ic_ptr = (int*)alloc(I + 1);
    int* cnt    = (int*)alloc(U);
    int* bsum   = (int*)alloc(SCAN2_B);
    int* sn_colc = (int*)alloc(Es);
    int* ci_colc = (int*)alloc(Eui);
    int* ic_colc = (int*)alloc(Eiu);
    float* att_sn1 = (float*)alloc(Es);
    float* att_sn2 = (float*)alloc(Es);
    float* att_ci1 = (float*)alloc(Eui);
    float* att_ci2 = (float*)alloc(Eui);
    float* att_ic1 = (float*)alloc(Eiu);
    float* att_ic2 = (float*)alloc(Eiu);
    float* rs_sn1 = (float*)alloc(U);
    float* rs_sn2 = (float*)alloc(U);
    float* rs_ci1 = (float*)alloc(U);
    float* rs_ci2 = (float*)alloc(U);
    float* rs_ic1 = (float*)alloc(I);
    float* rs_ic2 = (float*)alloc(I);
    float* u1  = (float*)alloc((size_t)U * DIM);
    float* i1  = (float*)alloc((size_t)I * DIM);
    float* u2s = (float*)alloc((size_t)B * DIM);
    float* i2s = (float*)alloc((size_t)B * DIM);
    (void)ws_size;

    // ---- CSR build + fused logit scatter + softmax for one edge set pair ----
    auto build_set = [&](const int* rows, const int* cols,
                         const float* raw1, const float* raw2, int j1, int j2,
                         int n_edges, int n_rows, int* ptr, int* colc,
                         float* att1, float* att2, float* rs1, float* rs2) {
        int eb = (n_edges + 255) / 256;
        int nb = (n_rows + SCAN_B - 1) / SCAN_B;
        hipMemsetAsync(cnt, 0, (size_t)n_rows * sizeof(int), stream);
        hist_kernel<<<eb, 256, 0, stream>>>(rows, cnt, n_edges);
        scan1_kernel<<<nb, SCAN_B, 0, stream>>>(cnt, ptr, bsum, n_rows);
        scan2_kernel<<<1, SCAN2_B, 0, stream>>>(bsum, nb);
        scan3_kernel<<<nb, SCAN_B, 0, stream>>>(ptr, bsum, n_rows, n_edges);
        hipMemsetAsync(cnt, 0, (size_t)n_rows * sizeof(int), stream);
        scatter_fused<<<eb, 256, 0, stream>>>(rows, cols, raw1, raw2, low_w, low_b,
                                              j1, j2, ptr, cnt, colc, att1, att2, n_edges);
        softmax_rows<<<(n_rows + 3) / 4, 256, 0, stream>>>(att1, att2, ptr, rs1, rs2, n_rows);
    };

    build_set(sn_row, sn_col, snii1, snii2, 0, 1, Es,  U, sn_ptr, sn_colc,
              att_sn1, att_sn2, rs_sn1, rs_sn2);
    build_set(ci_row, ci_col, ciii1, ciii2, 2, 3, Eui, U, ci_ptr, ci_colc,
              att_ci1, att_ci2, rs_ci1, rs_ci2);
    build_set(ic_row, ic_col, icii1, icii2, 4, 5, Eiu, I, ic_ptr, ic_colc,
              att_ic1, att_ic2, rs_ic1, rs_ic2);

    // ---- layer 1 (full) ----
    user_layer_fused<<<(U + 3) / 4, 256, 0, stream>>>(user_emb, item_emb,
        ci_ptr, ci_colc, att_ci1, rs_ci1, sn_ptr, sn_colc, att_sn1, rs_sn1,
        att1_W, att1_b, att2_w, att2_b, 0, u1, U, nullptr);
    item_layer_fused<<<(I + 3) / 4, 256, 0, stream>>>(item_emb, user_emb,
        ic_ptr, ic_colc, att_ic1, rs_ic1,
        att1_W, att1_b, att2_w, att2_b, 4, i1, I, nullptr);

    // ---- layer 2 (only at sampled rows) ----
    user_layer_fused<<<(B + 3) / 4, 256, 0, stream>>>(u1, i1,
        ci_ptr, ci_colc, att_ci2, rs_ci2, sn_ptr, sn_colc, att_sn2, rs_sn2,
        att1_W, att1_b, att2_w, att2_b, 2, u2s, B, user_idx);
    item_layer_fused<<<(B + 3) / 4, 256, 0, stream>>>(i1, u1,
        ic_ptr, ic_colc, att_ic2, rs_ic2,
        att1_W, att1_b, att2_w, att2_b, 6, i2s, B, item_idx);

    // ---- final gather-dot-sigmoid ----
    final_kernel<<<(B + 3) / 4, 256, 0, stream>>>(user_emb, u1, u2s, item_emb, i1, i2s,
                                                  user_idx, item_idx, out, B);
}

// Round 4
// 691.845 us; speedup vs baseline: 2.9793x; 1.0904x over previous
//
#include <hip/hip_runtime.h>
#include <math.h>

#define DIM 64
#define SCAN_B 512

typedef unsigned short ushort_t;
typedef unsigned int uint_t;

// ---------------- f32 -> bf16 conversion (RNE), u0 and i0 in one dispatch ----------------

__device__ __forceinline__ ushort_t f2bf(float f) {
    uint_t u = __float_as_uint(f);
    return (ushort_t)((u + 0x7fffu + ((u >> 16) & 1u)) >> 16);
}

__global__ void cvt_kernel(const float* __restrict__ u0, const float* __restrict__ i0,
                           ushort_t* __restrict__ ub, ushort_t* __restrict__ ib,
                           size_t n4_u, size_t n4_tot) {
    size_t i = (size_t)blockIdx.x * blockDim.x + threadIdx.x;
    if (i >= n4_tot) return;
    float4 v;
    ushort_t* dst;
    size_t di;
    if (i < n4_u) { v = ((const float4*)u0)[i]; dst = ub; di = i; }
    else          { v = ((const float4*)i0)[i - n4_u]; dst = ib; di = i - n4_u; }
    ushort_t o0 = f2bf(v.x), o1 = f2bf(v.y), o2 = f2bf(v.z), o3 = f2bf(v.w);
    uint_t p0 = (uint_t)o0 | ((uint_t)o1 << 16);
    uint_t p1 = (uint_t)o2 | ((uint_t)o3 << 16);
    ((uint2*)dst)[di] = make_uint2(p0, p1);
}

// ---------------- unified CSR build over virtual row space R = 2U + I ----------------

__global__ void hist_all(const int* __restrict__ sn_row, const int* __restrict__ ci_row,
                         const int* __restrict__ ic_row, int* __restrict__ cnt,
                         int Es, int Eui, int Eiu, int U) {
    int e = blockIdx.x * blockDim.x + threadIdx.x;
    int r;
    if (e < Es) r = sn_row[e];
    else if (e < Es + Eui) r = U + ci_row[e - Es];
    else if (e < Es + Eui + Eiu) r = 2 * U + ic_row[e - Es - Eui];
    else return;
    atomicAdd(&cnt[r], 1);
}

__global__ void scan1_kernel(const int* __restrict__ cnt, int* __restrict__ ptr,
                             int* __restrict__ bsum, int n) {
    __shared__ int sm[SCAN_B];
    int i = blockIdx.x * SCAN_B + threadIdx.x;
    int v = (i < n) ? cnt[i] : 0;
    sm[threadIdx.x] = v;
    __syncthreads();
    for (int off = 1; off < SCAN_B; off <<= 1) {
        int t = 0;
        if ((int)threadIdx.x >= off) t = sm[threadIdx.x - off];
        __syncthreads();
        if ((int)threadIdx.x >= off) sm[threadIdx.x] += t;
        __syncthreads();
    }
    if (i < n) ptr[i] = sm[threadIdx.x] - v;
    if (threadIdx.x == SCAN_B - 1) bsum[blockIdx.x] = sm[threadIdx.x];
}

__global__ void scan2_kernel(int* __restrict__ bsum, int nb) {
    __shared__ int sm[SCAN_B];
    int i = threadIdx.x;
    int v = (i < nb) ? bsum[i] : 0;
    sm[i] = v;
    __syncthreads();
    for (int off = 1; off < SCAN_B; off <<= 1) {
        int t = 0;
        if (i >= off) t = sm[i - off];
        __syncthreads();
        if (i >= off) sm[i] += t;
        __syncthreads();
    }
    if (i < nb) bsum[i] = sm[i] - v;
}

__global__ void scan3_kernel(int* __restrict__ ptr, const int* __restrict__ bsum,
                             int n, int total) {
    int i = blockIdx.x * SCAN_B + threadIdx.x;
    if (i < n) {
        ptr[i] += bsum[blockIdx.x];
        if (i == n - 1) ptr[n] = total;
    }
}

// scatter all 3 sets into CSR order; fuse edge_logit v = exp(sigmoid(raw*w+b))
__global__ void scatter_all(const int* __restrict__ sn_row, const int* __restrict__ sn_col,
                            const int* __restrict__ ci_row, const int* __restrict__ ci_col,
                            const int* __restrict__ ic_row, const int* __restrict__ ic_col,
                            const float* __restrict__ snii1, const float* __restrict__ snii2,
                            const float* __restrict__ ciii1, const float* __restrict__ ciii2,
                            const float* __restrict__ icii1, const float* __restrict__ icii2,
                            const float* __restrict__ lw, const float* __restrict__ lb,
                            const int* __restrict__ ptr, int* __restrict__ cnt,
                            int* __restrict__ colc, float* __restrict__ att1,
                            float* __restrict__ att2,
                            int Es, int Eui, int Eiu, int U) {
    int e = blockIdx.x * blockDim.x + threadIdx.x;
    int r, c, j1, j2;
    float r1, r2;
    if (e < Es) {
        r = sn_row[e]; c = sn_col[e]; r1 = snii1[e]; r2 = snii2[e]; j1 = 0; j2 = 1;
    } else if (e < Es + Eui) {
        int t = e - Es;
        r = U + ci_row[t]; c = ci_col[t]; r1 = ciii1[t]; r2 = ciii2[t]; j1 = 2; j2 = 3;
    } else if (e < Es + Eui + Eiu) {
        int t = e - Es - Eui;
        r = 2 * U + ic_row[t]; c = ic_col[t]; r1 = icii1[t]; r2 = icii2[t]; j1 = 4; j2 = 5;
    } else return;
    int pos = ptr[r] + atomicAdd(&cnt[r], 1);
    colc[pos] = c;
    att1[pos] = expf(1.0f / (1.0f + expf(-(r1 * lw[j1] + lb[j1]))));
    att2[pos] = expf(1.0f / (1.0f + expf(-(r2 * lw[j2] + lb[j2]))));
}

// ---------------- sparse softmax over all virtual rows (16-lane group per row) ----------------
// leaves att as unnormalized exp; stores reciprocal row sums

__global__ void softmax_all(float* __restrict__ att1, float* __restrict__ att2,
                            const int* __restrict__ ptr,
                            float* __restrict__ rs1, float* __restrict__ rs2, int R) {
    int grp = (blockIdx.x * blockDim.x + threadIdx.x) >> 4;
    int l = threadIdx.x & 15;
    if (grp >= R) return;
    int s0 = ptr[grp], s1 = ptr[grp + 1];
    float m1 = -1e30f, m2 = -1e30f;
    for (int e = s0 + l; e < s1; e += 16) {
        m1 = fmaxf(m1, att1[e]);
        m2 = fmaxf(m2, att2[e]);
    }
    #pragma unroll
    for (int off = 1; off < 16; off <<= 1) {
        m1 = fmaxf(m1, __shfl_xor(m1, off, 64));
        m2 = fmaxf(m2, __shfl_xor(m2, off, 64));
    }
    float sum1 = 0.0f, sum2 = 0.0f;
    for (int e = s0 + l; e < s1; e += 16) {
        float e1 = expf(att1[e] - m1); att1[e] = e1; sum1 += e1;
        float e2 = expf(att2[e] - m2); att2[e] = e2; sum2 += e2;
    }
    #pragma unroll
    for (int off = 1; off < 16; off <<= 1) {
        sum1 += __shfl_xor(sum1, off, 64);
        sum2 += __shfl_xor(sum2, off, 64);
    }
    if (l == 0) {
        rs1[grp] = 1.0f / (sum1 + 1e-12f);
        rs2[grp] = 1.0f / (sum2 + 1e-12f);
    }
}

// ---------------- layer kernels ----------------

__device__ __forceinline__ float att_scalar(float dot, float b1, float w2, float b2, float addc) {
    float h = tanhf(dot + b1);
    float z = h * w2 + b2;
    float lr = z > 0.0f ? z : 0.2f * z;   // leaky_relu alpha=0.2
    return expf(lr) + addc;
}

__device__ __forceinline__ void bf16_fma8(float acc[8], uint4 v, float a) {
    uint_t w[4] = {v.x, v.y, v.z, v.w};
    #pragma unroll
    for (int j = 0; j < 4; j++) {
        float lo = __uint_as_float(w[j] << 16);
        float hi = __uint_as_float(w[j] & 0xffff0000u);
        acc[2 * j]     = fmaf(a, lo, acc[2 * j]);
        acc[2 * j + 1] = fmaf(a, hi, acc[2 * j + 1]);
    }
}

__device__ __forceinline__ void xgroup_reduce8(float acc[8]) {
    #pragma unroll
    for (int j = 0; j < 8; j++) {
        #pragma unroll
        for (int off = 8; off < 64; off <<= 1)
            acc[j] += __shfl_xor(acc[j], off, 64);
    }
}

__device__ __forceinline__ float dot8_lanes(float d) {
    #pragma unroll
    for (int off = 1; off < 8; off <<= 1) d += __shfl_xor(d, off, 64);
    return d;
}

// layer 1 merged: waves [0,U) = user rows, [U,U+I) = item rows; bf16 gathers
__global__ void layer1_kernel(const ushort_t* __restrict__ ub, const ushort_t* __restrict__ ib,
                              const float* __restrict__ u0, const float* __restrict__ i0,
                              const int* __restrict__ ptr, const int* __restrict__ colc,
                              const float* __restrict__ att, const float* __restrict__ rs,
                              const float* __restrict__ W1, const float* __restrict__ b1v,
                              const float* __restrict__ w2v, const float* __restrict__ b2v,
                              float* __restrict__ u1, float* __restrict__ i1, int U, int I) {
    int wid = blockIdx.x * (blockDim.x >> 6) + (threadIdx.x >> 6);
    int lane = threadIdx.x & 63;
    if (wid >= U + I) return;
    int g = lane >> 3, l8 = lane & 7;
    bool is_user = wid < U;
    int r = is_user ? wid : wid - U;

    float acc_a[8] = {0, 0, 0, 0, 0, 0, 0, 0};   // ci (user) / ic (item)
    float acc_b[8] = {0, 0, 0, 0, 0, 0, 0, 0};   // sn (user only)

    if (is_user) {
        int e0 = ptr[U + r], e1 = ptr[U + r + 1];
        for (int e = e0 + g; e < e1; e += 8) {
            float a = att[e];
            int c = colc[e];
            uint4 v = ((const uint4*)(ib + (size_t)c * DIM))[l8];
            bf16_fma8(acc_a, v, a);
        }
        e0 = ptr[r]; e1 = ptr[r + 1];
        for (int e = e0 + g; e < e1; e += 8) {
            float a = att[e];
            int c = colc[e];
            uint4 v = ((const uint4*)(ub + (size_t)c * DIM))[l8];
            bf16_fma8(acc_b, v, a);
        }
        xgroup_reduce8(acc_a);
        xgroup_reduce8(acc_b);
    } else {
        int e0 = ptr[2 * U + r], e1 = ptr[2 * U + r + 1];
        for (int e = e0 + g; e < e1; e += 8) {
            float a = att[e];
            int c = colc[e];
            uint4 v = ((const uint4*)(ub + (size_t)c * DIM))[l8];
            bf16_fma8(acc_a, v, a);
        }
        xgroup_reduce8(acc_a);
    }

    if (g == 0) {   // lanes 0..7 finish the row
        const float* selfp = (is_user ? u0 : i0) + (size_t)r * DIM + 8 * l8;
        float4 s0 = *(const float4*)selfp;
        float4 s1 = *(const float4*)(selfp + 4);
        int k = is_user ? 0 : 4;
        const float* Wa = W1 + k * 2 * DIM;
        const float* Wb = Wa + 2 * DIM;
        float4 wa0a = *(const float4*)(Wa + 8 * l8);
        float4 wa0b = *(const float4*)(Wa + 8 * l8 + 4);
        float4 wa1a = *(const float4*)(Wa + DIM + 8 * l8);
        float4 wa1b = *(const float4*)(Wa + DIM + 8 * l8 + 4);
        float4 wb0a = *(const float4*)(Wb + 8 * l8);
        float4 wb0b = *(const float4*)(Wb + 8 * l8 + 4);
        float4 wb1a = *(const float4*)(Wb + DIM + 8 * l8);
        float4 wb1b = *(const float4*)(Wb + DIM + 8 * l8 + 4);

        float d1, d2, ra, rb = 0.f;
        if (is_user) {
            ra = rs[U + r]; rb = rs[r];
        } else {
            ra = rs[2 * U + r];
        }
        #pragma unroll
        for (int j = 0; j < 8; j++) acc_a[j] *= ra;
        if (is_user) {
            #pragma unroll
            for (int j = 0; j < 8; j++) acc_b[j] *= rb;
        }

        float sf[8] = {s0.x, s0.y, s0.z, s0.w, s1.x, s1.y, s1.z, s1.w};
        float w_a0[8] = {wa0a.x, wa0a.y, wa0a.z, wa0a.w, wa0b.x, wa0b.y, wa0b.z, wa0b.w};
        float w_a1[8] = {wa1a.x, wa1a.y, wa1a.z, wa1a.w, wa1b.x, wa1b.y, wa1b.z, wa1b.w};
        float w_b0[8] = {wb0a.x, wb0a.y, wb0a.z, wb0a.w, wb0b.x, wb0b.y, wb0b.z, wb0b.w};
        float w_b1[8] = {wb1a.x, wb1a.y, wb1a.z, wb1a.w, wb1b.x, wb1b.y, wb1b.z, wb1b.w};

        d1 = 0.f; d2 = 0.f;
        if (is_user) {
            #pragma unroll
            for (int j = 0; j < 8; j++) {
                d1 += sf[j] * w_a0[j] + acc_a[j] * w_a1[j];
                d2 += sf[j] * w_b0[j] + acc_b[j] * w_b1[j];
            }
        } else {
            #pragma unroll
            for (int j = 0; j < 8; j++) {
                d1 += sf[j] * (w_a0[j] + w_a1[j]);           // concat([it, it])
                d2 += sf[j] * w_b0[j] + acc_a[j] * w_b1[j];
            }
        }
        d1 = dot8_lanes(d1);
        d2 = dot8_lanes(d2);

        float out8[8];
        float* op;
        if (is_user) {
            float a_int = att_scalar(d1, b1v[0], w2v[0], b2v[0], 0.7f);
            float a_soc = att_scalar(d2, b1v[1], w2v[1], b2v[1], 0.3f);
            float sgate = a_int + a_soc;
            float wi = a_int / sgate, ws = a_soc / sgate;
            #pragma unroll
            for (int j = 0; j < 8; j++)
                out8[j] = 0.5f * sf[j] + 0.5f * (wi * acc_a[j] + ws * acc_b[j]);
            op = u1 + (size_t)r * DIM + 8 * l8;
        } else {
            float a_self = att_scalar(d1, b1v[4], w2v[4], b2v[4], 1.0f);
            float a_cust = att_scalar(d2, b1v[5], w2v[5], b2v[5], 1.0f);
            float sgate = a_self + a_cust;
            float wi = a_self / sgate, ws = a_cust / sgate;
            #pragma unroll
            for (int j = 0; j < 8; j++)
                out8[j] = wi * sf[j] + ws * acc_a[j];
            op = i1 + (size_t)r * DIM + 8 * l8;
        }
        *(float4*)op = make_float4(out8[0], out8[1], out8[2], out8[3]);
        *(float4*)(op + 4) = make_float4(out8[4], out8[5], out8[6], out8[7]);
    }
}

// layer 2 merged (sampled rows only): waves [0,B) user, [B,2B) item; f32 gathers from u1/i1
__global__ void layer2_kernel(const float* __restrict__ u1, const float* __restrict__ i1,
                              const int* __restrict__ ptr, const int* __restrict__ colc,
                              const float* __restrict__ att, const float* __restrict__ rs,
                              const float* __restrict__ W1, const float* __restrict__ b1v,
                              const float* __restrict__ w2v, const float* __restrict__ b2v,
                              const int* __restrict__ uidx, const int* __restrict__ iidx,
                              float* __restrict__ u2s, float* __restrict__ i2s, int U, int B) {
    int wid = blockIdx.x * (blockDim.x >> 6) + (threadIdx.x >> 6);
    int lane = threadIdx.x & 63;
    if (wid >= 2 * B) return;
    int g = lane >> 3, l8 = lane & 7;
    bool is_user = wid < B;
    int b = is_user ? wid : wid - B;
    int r = is_user ? uidx[b] : iidx[b];

    float acc_a[8] = {0, 0, 0, 0, 0, 0, 0, 0};
    float acc_b[8] = {0, 0, 0, 0, 0, 0, 0, 0};

    if (is_user) {
        int e0 = ptr[U + r], e1 = ptr[U + r + 1];
        for (int e = e0 + g; e < e1; e += 8) {
            float a = att[e];
            int c = colc[e];
            const float4* rp = (const float4*)(i1 + (size_t)c * DIM);
            float4 v0 = rp[2 * l8], v1 = rp[2 * l8 + 1];
            acc_a[0] = fmaf(a, v0.x, acc_a[0]); acc_a[1] = fmaf(a, v0.y, acc_a[1]);
            acc_a[2] = fmaf(a, v0.z, acc_a[2]); acc_a[3] = fmaf(a, v0.w, acc_a[3]);
            acc_a[4] = fmaf(a, v1.x, acc_a[4]); acc_a[5] = fmaf(a, v1.y, acc_a[5]);
            acc_a[6] = fmaf(a, v1.z, acc_a[6]); acc_a[7] = fmaf(a, v1.w, acc_a[7]);
        }
        e0 = ptr[r]; e1 = ptr[r + 1];
        for (int e = e0 + g; e < e1; e += 8) {
            float a = att[e];
            int c = colc[e];
            const float4* rp = (const float4*)(u1 + (size_t)c * DIM);
            float4 v0 = rp[2 * l8], v1 = rp[2 * l8 + 1];
            acc_b[0] = fmaf(a, v0.x, acc_b[0]); acc_b[1] = fmaf(a, v0.y, acc_b[1]);
            acc_b[2] = fmaf(a, v0.z, acc_b[2]); acc_b[3] = fmaf(a, v0.w, acc_b[3]);
            acc_b[4] = fmaf(a, v1.x, acc_b[4]); acc_b[5] = fmaf(a, v1.y, acc_b[5]);
            acc_b[6] = fmaf(a, v1.z, acc_b[6]); acc_b[7] = fmaf(a, v1.w, acc_b[7]);
        }
        xgroup_reduce8(acc_a);
        xgroup_reduce8(acc_b);
    } else {
        int e0 = ptr[2 * U + r], e1 = ptr[2 * U + r + 1];
        for (int e = e0 + g; e < e1; e += 8) {
            float a = att[e];
            int c = colc[e];
            const float4* rp = (const float4*)(u1 + (size_t)c * DIM);
            float4 v0 = rp[2 * l8], v1 = rp[2 * l8 + 1];
            acc_a[0] = fmaf(a, v0.x, acc_a[0]); acc_a[1] = fmaf(a, v0.y, acc_a[1]);
            acc_a[2] = fmaf(a, v0.z, acc_a[2]); acc_a[3] = fmaf(a, v0.w, acc_a[3]);
            acc_a[4] = fmaf(a, v1.x, acc_a[4]); acc_a[5] = fmaf(a, v1.y, acc_a[5]);
            acc_a[6] = fmaf(a, v1.z, acc_a[6]); acc_a[7] = fmaf(a, v1.w, acc_a[7]);
        }
        xgroup_reduce8(acc_a);
    }

    if (g == 0) {
        const float* selfp = (is_user ? u1 : i1) + (size_t)r * DIM + 8 * l8;
        float4 s0 = *(const float4*)selfp;
        float4 s1 = *(const float4*)(selfp + 4);
        int k = is_user ? 2 : 6;
        const float* Wa = W1 + k * 2 * DIM;
        const float* Wb = Wa + 2 * DIM;
        float4 wa0a = *(const float4*)(Wa + 8 * l8);
        float4 wa0b = *(const float4*)(Wa + 8 * l8 + 4);
        float4 wa1a = *(const float4*)(Wa + DIM + 8 * l8);
        float4 wa1b = *(const float4*)(Wa + DIM + 8 * l8 + 4);
        float4 wb0a = *(const float4*)(Wb + 8 * l8);
        float4 wb0b = *(const float4*)(Wb + 8 * l8 + 4);
        float4 wb1a = *(const float4*)(Wb + DIM + 8 * l8);
        float4 wb1b = *(const float4*)(Wb + DIM + 8 * l8 + 4);

        float ra, rb2 = 0.f;
        if (is_user) { ra = rs[U + r]; rb2 = rs[r]; }
        else         { ra = rs[2 * U + r]; }
        #pragma unroll
        for (int j = 0; j < 8; j++) acc_a[j] *= ra;
        if (is_user) {
            #pragma unroll
            for (int j = 0; j < 8; j++) acc_b[j] *= rb2;
        }

        float sf[8] = {s0.x, s0.y, s0.z, s0.w, s1.x, s1.y, s1.z, s1.w};
        float w_a0[8] = {wa0a.x, wa0a.y, wa0a.z, wa0a.w, wa0b.x, wa0b.y, wa0b.z, wa0b.w};
        float w_a1[8] = {wa1a.x, wa1a.y, wa1a.z, wa1a.w, wa1b.x, wa1b.y, wa1b.z, wa1b.w};
        float w_b0[8] = {wb0a.x, wb0a.y, wb0a.z, wb0a.w, wb0b.x, wb0b.y, wb0b.z, wb0b.w};
        float w_b1[8] = {wb1a.x, wb1a.y, wb1a.z, wb1a.w, wb1b.x, wb1b.y, wb1b.z, wb1b.w};

        float d1 = 0.f, d2 = 0.f;
        if (is_user) {
            #pragma unroll
            for (int j = 0; j < 8; j++) {
                d1 += sf[j] * w_a0[j] + acc_a[j] * w_a1[j];
                d2 += sf[j] * w_b0[j] + acc_b[j] * w_b1[j];
            }
        } else {
            #pragma unroll
            for (int j = 0; j < 8; j++) {
                d1 += sf[j] * (w_a0[j] + w_a1[j]);
                d2 += sf[j] * w_b0[j] + acc_a[j] * w_b1[j];
            }
        }
        d1 = dot8_lanes(d1);
        d2 = dot8_lanes(d2);

        float out8[8];
        float* op;
        if (is_user) {
            float a_int = att_scalar(d1, b1v[2], w2v[2], b2v[2], 0.7f);
            float a_soc = att_scalar(d2, b1v[3], w2v[3], b2v[3], 0.3f);
            float sgate = a_int + a_soc;
            float wi = a_int / sgate, ws = a_soc / sgate;
            #pragma unroll
            for (int j = 0; j < 8; j++)
                out8[j] = 0.5f * sf[j] + 0.5f * (wi * acc_a[j] + ws * acc_b[j]);
            op = u2s + (size_t)b * DIM + 8 * l8;
        } else {
            float a_self = att_scalar(d1, b1v[6], w2v[6], b2v[6], 1.0f);
            float a_cust = att_scalar(d2, b1v[7], w2v[7], b2v[7], 1.0f);
            float sgate = a_self + a_cust;
            float wi = a_self / sgate, ws = a_cust / sgate;
            #pragma unroll
            for (int j = 0; j < 8; j++)
                out8[j] = wi * sf[j] + ws * acc_a[j];
            op = i2s + (size_t)b * DIM + 8 * l8;
        }
        *(float4*)op = make_float4(out8[0], out8[1], out8[2], out8[3]);
        *(float4*)(op + 4) = make_float4(out8[4], out8[5], out8[6], out8[7]);
    }
}

// ---------------- final: sigmoid(dot over [u0|u1|u2] . [i0|i1|i2]) ----------------

__global__ void final_kernel(const float* __restrict__ u0, const float* __restrict__ u1,
                             const float* __restrict__ u2s,
                             const float* __restrict__ i0, const float* __restrict__ i1,
                             const float* __restrict__ i2s,
                             const int* __restrict__ uidx, const int* __restrict__ iidx,
                             float* __restrict__ out, int n) {
    int b = blockIdx.x * (blockDim.x >> 6) + (threadIdx.x >> 6);
    int lane = threadIdx.x & 63;
    if (b >= n) return;
    size_t ur = (size_t)uidx[b] * DIM + lane;
    size_t ir = (size_t)iidx[b] * DIM + lane;
    size_t sr = (size_t)b * DIM + lane;
    float acc = u0[ur] * i0[ir] + u1[ur] * i1[ir] + u2s[sr] * i2s[sr];
    #pragma unroll
    for (int off = 32; off > 0; off >>= 1) acc += __shfl_xor(acc, off, 64);
    if (lane == 0) out[b] = 1.0f / (1.0f + expf(-acc));
}

// ---------------- launch ----------------

extern "C" void kernel_launch(void* const* d_in, const int* in_sizes, int n_in,
                              void* d_out, int out_size, void* d_ws, size_t ws_size,
                              hipStream_t stream) {
    const float* user_emb = (const float*)d_in[0];
    const float* item_emb = (const float*)d_in[1];
    const float* snii1 = (const float*)d_in[2];
    const float* snii2 = (const float*)d_in[3];
    const float* ciii1 = (const float*)d_in[4];
    const float* ciii2 = (const float*)d_in[5];
    const float* icii1 = (const float*)d_in[6];
    const float* icii2 = (const float*)d_in[7];
    const float* low_w = (const float*)d_in[8];
    const float* low_b = (const float*)d_in[9];
    const float* att1_W = (const float*)d_in[10];
    const float* att1_b = (const float*)d_in[11];
    const float* att2_w = (const float*)d_in[12];
    const float* att2_b = (const float*)d_in[13];
    const int* sn_row = (const int*)d_in[14];
    const int* sn_col = (const int*)d_in[15];
    const int* ci_row = (const int*)d_in[16];
    const int* ci_col = (const int*)d_in[17];
    const int* ic_row = (const int*)d_in[18];
    const int* ic_col = (const int*)d_in[19];
    const int* user_idx = (const int*)d_in[20];
    const int* item_idx = (const int*)d_in[21];
    float* out = (float*)d_out;

    const int Es  = in_sizes[2];
    const int Eui = in_sizes[4];
    const int Eiu = in_sizes[6];
    const int U = in_sizes[0] / DIM;
    const int I = in_sizes[1] / DIM;
    const int B = in_sizes[20];
    const int R = 2 * U + I;           // virtual row space: [0,U)=sn, [U,2U)=ci, [2U,2U+I)=ic
    const int E = Es + Eui + Eiu;

    // ---- workspace carve (4-byte units, 16B-aligned) ----
    char* wsb = (char*)d_ws;
    size_t off = 0;
    auto alloc = [&](size_t n_units) {
        off = (off + 3) & ~(size_t)3;
        void* p = wsb + off * 4; off += n_units; return p;
    };

    int* ptr   = (int*)alloc(R + 1);
    int* cnt   = (int*)alloc(R);
    int* bsum  = (int*)alloc(SCAN_B);
    int* colc  = (int*)alloc(E);
    float* att1 = (float*)alloc(E);
    float* att2 = (float*)alloc(E);
    float* rs1  = (float*)alloc(R);
    float* rs2  = (float*)alloc(R);
    ushort_t* ub16 = (ushort_t*)alloc((size_t)U * DIM / 2);
    ushort_t* ib16 = (ushort_t*)alloc((size_t)I * DIM / 2);
    float* u1  = (float*)alloc((size_t)U * DIM);
    float* i1  = (float*)alloc((size_t)I * DIM);
    float* u2s = (float*)alloc((size_t)B * DIM);
    float* i2s = (float*)alloc((size_t)B * DIM);
    (void)ws_size;

    // ---- bf16 tables for layer-1 gathers ----
    size_t n4u = (size_t)U * DIM / 4, n4t = (size_t)(U + I) * DIM / 4;
    cvt_kernel<<<(int)((n4t + 255) / 256), 256, 0, stream>>>(user_emb, item_emb,
                                                             ub16, ib16, n4u, n4t);

    // ---- unified CSR build + fused edge logits + softmax ----
    int eb = (E + 255) / 256;
    int nb = (R + SCAN_B - 1) / SCAN_B;    // 489 <= 512
    hipMemsetAsync(cnt, 0, (size_t)R * sizeof(int), stream);
    hist_all<<<eb, 256, 0, stream>>>(sn_row, ci_row, ic_row, cnt, Es, Eui, Eiu, U);
    scan1_kernel<<<nb, SCAN_B, 0, stream>>>(cnt, ptr, bsum, R);
    scan2_kernel<<<1, SCAN_B, 0, stream>>>(bsum, nb);
    scan3_kernel<<<nb, SCAN_B, 0, stream>>>(ptr, bsum, R, E);
    hipMemsetAsync(cnt, 0, (size_t)R * sizeof(int), stream);
    scatter_all<<<eb, 256, 0, stream>>>(sn_row, sn_col, ci_row, ci_col, ic_row, ic_col,
                                        snii1, snii2, ciii1, ciii2, icii1, icii2,
                                        low_w, low_b, ptr, cnt, colc, att1, att2,
                                        Es, Eui, Eiu, U);
    softmax_all<<<(R + 15) / 16, 256, 0, stream>>>(att1, att2, ptr, rs1, rs2, R);

    // ---- layer 1 (merged user+item, full) ----
    layer1_kernel<<<(U + I + 3) / 4, 256, 0, stream>>>(ub16, ib16, user_emb, item_emb,
        ptr, colc, att1, rs1, att1_W, att1_b, att2_w, att2_b, u1, i1, U, I);

    // ---- layer 2 (merged, sampled rows only) ----
    layer2_kernel<<<(2 * B + 3) / 4, 256, 0, stream>>>(u1, i1, ptr, colc, att2, rs2,
        att1_W, att1_b, att2_w, att2_b, user_idx, item_idx, u2s, i2s, U, B);

    // ---- final gather-dot-sigmoid ----
    final_kernel<<<(B + 3) / 4, 256, 0, stream>>>(user_emb, u1, u2s, item_emb, i1, i2s,
                                                  user_idx, item_idx, out, B);
}

// Round 5
// 553.519 us; speedup vs baseline: 3.7238x; 1.2499x over previous
//
#include <hip/hip_runtime.h>
#include <math.h>

#define DIM 64
#define SCAN_B 512

typedef unsigned short ushort_t;
typedef unsigned int uint_t;

// ---------------- f32 -> bf16 conversion (RNE), u0 and i0 in one dispatch ----------------

__device__ __forceinline__ ushort_t f2bf(float f) {
    uint_t u = __float_as_uint(f);
    return (ushort_t)((u + 0x7fffu + ((u >> 16) & 1u)) >> 16);
}

__global__ void cvt_kernel(const float* __restrict__ u0, const float* __restrict__ i0,
                           ushort_t* __restrict__ ub, ushort_t* __restrict__ ib,
                           size_t n4_u, size_t n4_tot) {
    size_t i = (size_t)blockIdx.x * blockDim.x + threadIdx.x;
    if (i >= n4_tot) return;
    float4 v;
    ushort_t* dst;
    size_t di;
    if (i < n4_u) { v = ((const float4*)u0)[i]; dst = ub; di = i; }
    else          { v = ((const float4*)i0)[i - n4_u]; dst = ib; di = i - n4_u; }
    ushort_t o0 = f2bf(v.x), o1 = f2bf(v.y), o2 = f2bf(v.z), o3 = f2bf(v.w);
    uint_t p0 = (uint_t)o0 | ((uint_t)o1 << 16);
    uint_t p1 = (uint_t)o2 | ((uint_t)o3 << 16);
    ((uint2*)dst)[di] = make_uint2(p0, p1);
}

// ---------------- unified CSR build over virtual row space R = 2U + I ----------------
// hist also records each edge's within-row rank (coalesced write) so the scatter
// pass needs no atomics.

__global__ void hist_all(const int* __restrict__ sn_row, const int* __restrict__ ci_row,
                         const int* __restrict__ ic_row, int* __restrict__ cnt,
                         int* __restrict__ rank, int Es, int Eui, int Eiu, int U) {
    int e = blockIdx.x * blockDim.x + threadIdx.x;
    int r;
    if (e < Es) r = sn_row[e];
    else if (e < Es + Eui) r = U + ci_row[e - Es];
    else if (e < Es + Eui + Eiu) r = 2 * U + ic_row[e - Es - Eui];
    else return;
    rank[e] = atomicAdd(&cnt[r], 1);
}

__global__ void scan1_kernel(const int* __restrict__ cnt, int* __restrict__ ptr,
                             int* __restrict__ bsum, int n) {
    __shared__ int sm[SCAN_B];
    int i = blockIdx.x * SCAN_B + threadIdx.x;
    int v = (i < n) ? cnt[i] : 0;
    sm[threadIdx.x] = v;
    __syncthreads();
    for (int off = 1; off < SCAN_B; off <<= 1) {
        int t = 0;
        if ((int)threadIdx.x >= off) t = sm[threadIdx.x - off];
        __syncthreads();
        if ((int)threadIdx.x >= off) sm[threadIdx.x] += t;
        __syncthreads();
    }
    if (i < n) ptr[i] = sm[threadIdx.x] - v;
    if (threadIdx.x == SCAN_B - 1) bsum[blockIdx.x] = sm[threadIdx.x];
}

__global__ void scan2_kernel(int* __restrict__ bsum, int nb) {
    __shared__ int sm[SCAN_B];
    int i = threadIdx.x;
    int v = (i < nb) ? bsum[i] : 0;
    sm[i] = v;
    __syncthreads();
    for (int off = 1; off < SCAN_B; off <<= 1) {
        int t = 0;
        if (i >= off) t = sm[i - off];
        __syncthreads();
        if (i >= off) sm[i] += t;
        __syncthreads();
    }
    if (i < nb) bsum[i] = sm[i] - v;
}

__global__ void scan3_kernel(int* __restrict__ ptr, const int* __restrict__ bsum,
                             int n, int total) {
    int i = blockIdx.x * SCAN_B + threadIdx.x;
    if (i < n) {
        ptr[i] += bsum[blockIdx.x];
        if (i == n - 1) ptr[n] = total;
    }
}

// scatter all 3 sets into CSR order as packed 16B records {col, v1, v2, 0};
// one dwordx4 store per edge (single dirty line), no atomics (rank precomputed).
__global__ void scatter_all(const int* __restrict__ sn_row, const int* __restrict__ sn_col,
                            const int* __restrict__ ci_row, const int* __restrict__ ci_col,
                            const int* __restrict__ ic_row, const int* __restrict__ ic_col,
                            const float* __restrict__ snii1, const float* __restrict__ snii2,
                            const float* __restrict__ ciii1, const float* __restrict__ ciii2,
                            const float* __restrict__ icii1, const float* __restrict__ icii2,
                            const float* __restrict__ lw, const float* __restrict__ lb,
                            const int* __restrict__ ptr, const int* __restrict__ rank,
                            uint4* __restrict__ rec,
                            int Es, int Eui, int Eiu, int U) {
    int e = blockIdx.x * blockDim.x + threadIdx.x;
    int r, c, j1, j2;
    float r1, r2;
    if (e < Es) {
        r = sn_row[e]; c = sn_col[e]; r1 = snii1[e]; r2 = snii2[e]; j1 = 0; j2 = 1;
    } else if (e < Es + Eui) {
        int t = e - Es;
        r = U + ci_row[t]; c = ci_col[t]; r1 = ciii1[t]; r2 = ciii2[t]; j1 = 2; j2 = 3;
    } else if (e < Es + Eui + Eiu) {
        int t = e - Es - Eui;
        r = 2 * U + ic_row[t]; c = ic_col[t]; r1 = icii1[t]; r2 = icii2[t]; j1 = 4; j2 = 5;
    } else return;
    float v1 = expf(1.0f / (1.0f + expf(-(r1 * lw[j1] + lb[j1]))));
    float v2 = expf(1.0f / (1.0f + expf(-(r2 * lw[j2] + lb[j2]))));
    int pos = ptr[r] + rank[e];
    rec[pos] = make_uint4((uint_t)c, __float_as_uint(v1), __float_as_uint(v2), 0u);
}

// ---------------- sparse softmax over all virtual rows (16-lane group per row) ----------------
// rewrites rec.v1/.v2 to unnormalized exp; stores reciprocal row sums

__global__ void softmax_all(uint4* __restrict__ rec, const int* __restrict__ ptr,
                            float* __restrict__ rs1, float* __restrict__ rs2, int R) {
    int grp = (blockIdx.x * blockDim.x + threadIdx.x) >> 4;
    int l = threadIdx.x & 15;
    if (grp >= R) return;
    int s0 = ptr[grp], s1 = ptr[grp + 1];
    float m1 = -1e30f, m2 = -1e30f;
    for (int e = s0 + l; e < s1; e += 16) {
        uint4 q = rec[e];
        m1 = fmaxf(m1, __uint_as_float(q.y));
        m2 = fmaxf(m2, __uint_as_float(q.z));
    }
    #pragma unroll
    for (int off = 1; off < 16; off <<= 1) {
        m1 = fmaxf(m1, __shfl_xor(m1, off, 64));
        m2 = fmaxf(m2, __shfl_xor(m2, off, 64));
    }
    float sum1 = 0.0f, sum2 = 0.0f;
    for (int e = s0 + l; e < s1; e += 16) {
        uint4 q = rec[e];
        float e1 = expf(__uint_as_float(q.y) - m1);
        float e2 = expf(__uint_as_float(q.z) - m2);
        q.y = __float_as_uint(e1);
        q.z = __float_as_uint(e2);
        rec[e] = q;
        sum1 += e1; sum2 += e2;
    }
    #pragma unroll
    for (int off = 1; off < 16; off <<= 1) {
        sum1 += __shfl_xor(sum1, off, 64);
        sum2 += __shfl_xor(sum2, off, 64);
    }
    if (l == 0) {
        rs1[grp] = 1.0f / (sum1 + 1e-12f);
        rs2[grp] = 1.0f / (sum2 + 1e-12f);
    }
}

// ---------------- layer kernels ----------------

__device__ __forceinline__ float att_scalar(float dot, float b1, float w2, float b2, float addc) {
    float h = tanhf(dot + b1);
    float z = h * w2 + b2;
    float lr = z > 0.0f ? z : 0.2f * z;   // leaky_relu alpha=0.2
    return expf(lr) + addc;
}

__device__ __forceinline__ void bf16_fma8(float acc[8], uint4 v, float a) {
    uint_t w[4] = {v.x, v.y, v.z, v.w};
    #pragma unroll
    for (int j = 0; j < 4; j++) {
        float lo = __uint_as_float(w[j] << 16);
        float hi = __uint_as_float(w[j] & 0xffff0000u);
        acc[2 * j]     = fmaf(a, lo, acc[2 * j]);
        acc[2 * j + 1] = fmaf(a, hi, acc[2 * j + 1]);
    }
}

__device__ __forceinline__ void xgroup_reduce8(float acc[8]) {
    #pragma unroll
    for (int j = 0; j < 8; j++) {
        #pragma unroll
        for (int off = 8; off < 64; off <<= 1)
            acc[j] += __shfl_xor(acc[j], off, 64);
    }
}

__device__ __forceinline__ float dot8_lanes(float d) {
    #pragma unroll
    for (int off = 1; off < 8; off <<= 1) d += __shfl_xor(d, off, 64);
    return d;
}

// layer 1 merged: waves [0,U) = user rows, [U,U+I) = item rows; bf16 gathers
__global__ void layer1_kernel(const ushort_t* __restrict__ ub, const ushort_t* __restrict__ ib,
                              const float* __restrict__ u0, const float* __restrict__ i0,
                              const int* __restrict__ ptr, const uint4* __restrict__ rec,
                              const float* __restrict__ rs,
                              const float* __restrict__ W1, const float* __restrict__ b1v,
                              const float* __restrict__ w2v, const float* __restrict__ b2v,
                              float* __restrict__ u1, float* __restrict__ i1, int U, int I) {
    int wid = blockIdx.x * (blockDim.x >> 6) + (threadIdx.x >> 6);
    int lane = threadIdx.x & 63;
    if (wid >= U + I) return;
    int g = lane >> 3, l8 = lane & 7;
    bool is_user = wid < U;
    int r = is_user ? wid : wid - U;

    float acc_a[8] = {0, 0, 0, 0, 0, 0, 0, 0};   // ci (user) / ic (item)
    float acc_b[8] = {0, 0, 0, 0, 0, 0, 0, 0};   // sn (user only)

    if (is_user) {
        int e0 = ptr[U + r], e1 = ptr[U + r + 1];
        for (int e = e0 + g; e < e1; e += 8) {
            uint4 q = rec[e];
            float a = __uint_as_float(q.y);
            uint4 v = ((const uint4*)(ib + (size_t)q.x * DIM))[l8];
            bf16_fma8(acc_a, v, a);
        }
        e0 = ptr[r]; e1 = ptr[r + 1];
        for (int e = e0 + g; e < e1; e += 8) {
            uint4 q = rec[e];
            float a = __uint_as_float(q.y);
            uint4 v = ((const uint4*)(ub + (size_t)q.x * DIM))[l8];
            bf16_fma8(acc_b, v, a);
        }
        xgroup_reduce8(acc_a);
        xgroup_reduce8(acc_b);
    } else {
        int e0 = ptr[2 * U + r], e1 = ptr[2 * U + r + 1];
        for (int e = e0 + g; e < e1; e += 8) {
            uint4 q = rec[e];
            float a = __uint_as_float(q.y);
            uint4 v = ((const uint4*)(ub + (size_t)q.x * DIM))[l8];
            bf16_fma8(acc_a, v, a);
        }
        xgroup_reduce8(acc_a);
    }

    if (g == 0) {   // lanes 0..7 finish the row
        const float* selfp = (is_user ? u0 : i0) + (size_t)r * DIM + 8 * l8;
        float4 s0 = *(const float4*)selfp;
        float4 s1 = *(const float4*)(selfp + 4);
        int k = is_user ? 0 : 4;
        const float* Wa = W1 + k * 2 * DIM;
        const float* Wb = Wa + 2 * DIM;
        float4 wa0a = *(const float4*)(Wa + 8 * l8);
        float4 wa0b = *(const float4*)(Wa + 8 * l8 + 4);
        float4 wa1a = *(const float4*)(Wa + DIM + 8 * l8);
        float4 wa1b = *(const float4*)(Wa + DIM + 8 * l8 + 4);
        float4 wb0a = *(const float4*)(Wb + 8 * l8);
        float4 wb0b = *(const float4*)(Wb + 8 * l8 + 4);
        float4 wb1a = *(const float4*)(Wb + DIM + 8 * l8);
        float4 wb1b = *(const float4*)(Wb + DIM + 8 * l8 + 4);

        float ra, rb = 0.f;
        if (is_user) { ra = rs[U + r]; rb = rs[r]; }
        else         { ra = rs[2 * U + r]; }
        #pragma unroll
        for (int j = 0; j < 8; j++) acc_a[j] *= ra;
        if (is_user) {
            #pragma unroll
            for (int j = 0; j < 8; j++) acc_b[j] *= rb;
        }

        float sf[8] = {s0.x, s0.y, s0.z, s0.w, s1.x, s1.y, s1.z, s1.w};
        float w_a0[8] = {wa0a.x, wa0a.y, wa0a.z, wa0a.w, wa0b.x, wa0b.y, wa0b.z, wa0b.w};
        float w_a1[8] = {wa1a.x, wa1a.y, wa1a.z, wa1a.w, wa1b.x, wa1b.y, wa1b.z, wa1b.w};
        float w_b0[8] = {wb0a.x, wb0a.y, wb0a.z, wb0a.w, wb0b.x, wb0b.y, wb0b.z, wb0b.w};
        float w_b1[8] = {wb1a.x, wb1a.y, wb1a.z, wb1a.w, wb1b.x, wb1b.y, wb1b.z, wb1b.w};

        float d1 = 0.f, d2 = 0.f;
        if (is_user) {
            #pragma unroll
            for (int j = 0; j < 8; j++) {
                d1 += sf[j] * w_a0[j] + acc_a[j] * w_a1[j];
                d2 += sf[j] * w_b0[j] + acc_b[j] * w_b1[j];
            }
        } else {
            #pragma unroll
            for (int j = 0; j < 8; j++) {
                d1 += sf[j] * (w_a0[j] + w_a1[j]);           // concat([it, it])
                d2 += sf[j] * w_b0[j] + acc_a[j] * w_b1[j];
            }
        }
        d1 = dot8_lanes(d1);
        d2 = dot8_lanes(d2);

        float out8[8];
        float* op;
        if (is_user) {
            float a_int = att_scalar(d1, b1v[0], w2v[0], b2v[0], 0.7f);
            float a_soc = att_scalar(d2, b1v[1], w2v[1], b2v[1], 0.3f);
            float sgate = a_int + a_soc;
            float wi = a_int / sgate, ws = a_soc / sgate;
            #pragma unroll
            for (int j = 0; j < 8; j++)
                out8[j] = 0.5f * sf[j] + 0.5f * (wi * acc_a[j] + ws * acc_b[j]);
            op = u1 + (size_t)r * DIM + 8 * l8;
        } else {
            float a_self = att_scalar(d1, b1v[4], w2v[4], b2v[4], 1.0f);
            float a_cust = att_scalar(d2, b1v[5], w2v[5], b2v[5], 1.0f);
            float sgate = a_self + a_cust;
            float wi = a_self / sgate, ws = a_cust / sgate;
            #pragma unroll
            for (int j = 0; j < 8; j++)
                out8[j] = wi * sf[j] + ws * acc_a[j];
            op = i1 + (size_t)r * DIM + 8 * l8;
        }
        *(float4*)op = make_float4(out8[0], out8[1], out8[2], out8[3]);
        *(float4*)(op + 4) = make_float4(out8[4], out8[5], out8[6], out8[7]);
    }
}

// layer 2 merged (sampled rows only): waves [0,B) user, [B,2B) item; f32 gathers from u1/i1
__global__ void layer2_kernel(const float* __restrict__ u1, const float* __restrict__ i1,
                              const int* __restrict__ ptr, const uint4* __restrict__ rec,
                              const float* __restrict__ rs,
                              const float* __restrict__ W1, const float* __restrict__ b1v,
                              const float* __restrict__ w2v, const float* __restrict__ b2v,
                              const int* __restrict__ uidx, const int* __restrict__ iidx,
                              float* __restrict__ u2s, float* __restrict__ i2s, int U, int B) {
    int wid = blockIdx.x * (blockDim.x >> 6) + (threadIdx.x >> 6);
    int lane = threadIdx.x & 63;
    if (wid >= 2 * B) return;
    int g = lane >> 3, l8 = lane & 7;
    bool is_user = wid < B;
    int b = is_user ? wid : wid - B;
    int r = is_user ? uidx[b] : iidx[b];

    float acc_a[8] = {0, 0, 0, 0, 0, 0, 0, 0};
    float acc_b[8] = {0, 0, 0, 0, 0, 0, 0, 0};

    if (is_user) {
        int e0 = ptr[U + r], e1 = ptr[U + r + 1];
        for (int e = e0 + g; e < e1; e += 8) {
            uint4 q = rec[e];
            float a = __uint_as_float(q.z);
            const float4* rp = (const float4*)(i1 + (size_t)q.x * DIM);
            float4 v0 = rp[2 * l8], v1 = rp[2 * l8 + 1];
            acc_a[0] = fmaf(a, v0.x, acc_a[0]); acc_a[1] = fmaf(a, v0.y, acc_a[1]);
            acc_a[2] = fmaf(a, v0.z, acc_a[2]); acc_a[3] = fmaf(a, v0.w, acc_a[3]);
            acc_a[4] = fmaf(a, v1.x, acc_a[4]); acc_a[5] = fmaf(a, v1.y, acc_a[5]);
            acc_a[6] = fmaf(a, v1.z, acc_a[6]); acc_a[7] = fmaf(a, v1.w, acc_a[7]);
        }
        e0 = ptr[r]; e1 = ptr[r + 1];
        for (int e = e0 + g; e < e1; e += 8) {
            uint4 q = rec[e];
            float a = __uint_as_float(q.z);
            const float4* rp = (const float4*)(u1 + (size_t)q.x * DIM);
            float4 v0 = rp[2 * l8], v1 = rp[2 * l8 + 1];
            acc_b[0] = fmaf(a, v0.x, acc_b[0]); acc_b[1] = fmaf(a, v0.y, acc_b[1]);
            acc_b[2] = fmaf(a, v0.z, acc_b[2]); acc_b[3] = fmaf(a, v0.w, acc_b[3]);
            acc_b[4] = fmaf(a, v1.x, acc_b[4]); acc_b[5] = fmaf(a, v1.y, acc_b[5]);
            acc_b[6] = fmaf(a, v1.z, acc_b[6]); acc_b[7] = fmaf(a, v1.w, acc_b[7]);
        }
        xgroup_reduce8(acc_a);
        xgroup_reduce8(acc_b);
    } else {
        int e0 = ptr[2 * U + r], e1 = ptr[2 * U + r + 1];
        for (int e = e0 + g; e < e1; e += 8) {
            uint4 q = rec[e];
            float a = __uint_as_float(q.z);
            const float4* rp = (const float4*)(u1 + (size_t)q.x * DIM);
            float4 v0 = rp[2 * l8], v1 = rp[2 * l8 + 1];
            acc_a[0] = fmaf(a, v0.x, acc_a[0]); acc_a[1] = fmaf(a, v0.y, acc_a[1]);
            acc_a[2] = fmaf(a, v0.z, acc_a[2]); acc_a[3] = fmaf(a, v0.w, acc_a[3]);
            acc_a[4] = fmaf(a, v1.x, acc_a[4]); acc_a[5] = fmaf(a, v1.y, acc_a[5]);
            acc_a[6] = fmaf(a, v1.z, acc_a[6]); acc_a[7] = fmaf(a, v1.w, acc_a[7]);
        }
        xgroup_reduce8(acc_a);
    }

    if (g == 0) {
        const float* selfp = (is_user ? u1 : i1) + (size_t)r * DIM + 8 * l8;
        float4 s0 = *(const float4*)selfp;
        float4 s1 = *(const float4*)(selfp + 4);
        int k = is_user ? 2 : 6;
        const float* Wa = W1 + k * 2 * DIM;
        const float* Wb = Wa + 2 * DIM;
        float4 wa0a = *(const float4*)(Wa + 8 * l8);
        float4 wa0b = *(const float4*)(Wa + 8 * l8 + 4);
        float4 wa1a = *(const float4*)(Wa + DIM + 8 * l8);
        float4 wa1b = *(const float4*)(Wa + DIM + 8 * l8 + 4);
        float4 wb0a = *(const float4*)(Wb + 8 * l8);
        float4 wb0b = *(const float4*)(Wb + 8 * l8 + 4);
        float4 wb1a = *(const float4*)(Wb + DIM + 8 * l8);
        float4 wb1b = *(const float4*)(Wb + DIM + 8 * l8 + 4);

        float ra, rb2 = 0.f;
        if (is_user) { ra = rs[U + r]; rb2 = rs[r]; }
        else         { ra = rs[2 * U + r]; }
        #pragma unroll
        for (int j = 0; j < 8; j++) acc_a[j] *= ra;
        if (is_user) {
            #pragma unroll
            for (int j = 0; j < 8; j++) acc_b[j] *= rb2;
        }

        float sf[8] = {s0.x, s0.y, s0.z, s0.w, s1.x, s1.y, s1.z, s1.w};
        float w_a0[8] = {wa0a.x, wa0a.y, wa0a.z, wa0a.w, wa0b.x, wa0b.y, wa0b.z, wa0b.w};
        float w_a1[8] = {wa1a.x, wa1a.y, wa1a.z, wa1a.w, wa1b.x, wa1b.y, wa1b.z, wa1b.w};
        float w_b0[8] = {wb0a.x, wb0a.y, wb0a.z, wb0a.w, wb0b.x, wb0b.y, wb0b.z, wb0b.w};
        float w_b1[8] = {wb1a.x, wb1a.y, wb1a.z, wb1a.w, wb1b.x, wb1b.y, wb1b.z, wb1b.w};

        float d1 = 0.f, d2 = 0.f;
        if (is_user) {
            #pragma unroll
            for (int j = 0; j < 8; j++) {
                d1 += sf[j] * w_a0[j] + acc_a[j] * w_a1[j];
                d2 += sf[j] * w_b0[j] + acc_b[j] * w_b1[j];
            }
        } else {
            #pragma unroll
            for (int j = 0; j < 8; j++) {
                d1 += sf[j] * (w_a0[j] + w_a1[j]);
                d2 += sf[j] * w_b0[j] + acc_a[j] * w_b1[j];
            }
        }
        d1 = dot8_lanes(d1);
        d2 = dot8_lanes(d2);

        float out8[8];
        float* op;
        if (is_user) {
            float a_int = att_scalar(d1, b1v[2], w2v[2], b2v[2], 0.7f);
            float a_soc = att_scalar(d2, b1v[3], w2v[3], b2v[3], 0.3f);
            float sgate = a_int + a_soc;
            float wi = a_int / sgate, ws = a_soc / sgate;
            #pragma unroll
            for (int j = 0; j < 8; j++)
                out8[j] = 0.5f * sf[j] + 0.5f * (wi * acc_a[j] + ws * acc_b[j]);
            op = u2s + (size_t)b * DIM + 8 * l8;
        } else {
            float a_self = att_scalar(d1, b1v[6], w2v[6], b2v[6], 1.0f);
            float a_cust = att_scalar(d2, b1v[7], w2v[7], b2v[7], 1.0f);
            float sgate = a_self + a_cust;
            float wi = a_self / sgate, ws = a_cust / sgate;
            #pragma unroll
            for (int j = 0; j < 8; j++)
                out8[j] = wi * sf[j] + ws * acc_a[j];
            op = i2s + (size_t)b * DIM + 8 * l8;
        }
        *(float4*)op = make_float4(out8[0], out8[1], out8[2], out8[3]);
        *(float4*)(op + 4) = make_float4(out8[4], out8[5], out8[6], out8[7]);
    }
}

// ---------------- final: sigmoid(dot over [u0|u1|u2] . [i0|i1|i2]) ----------------

__global__ void final_kernel(const float* __restrict__ u0, const float* __restrict__ u1,
                             const float* __restrict__ u2s,
                             const float* __restrict__ i0, const float* __restrict__ i1,
                             const float* __restrict__ i2s,
                             const int* __restrict__ uidx, const int* __restrict__ iidx,
                             float* __restrict__ out, int n) {
    int b = blockIdx.x * (blockDim.x >> 6) + (threadIdx.x >> 6);
    int lane = threadIdx.x & 63;
    if (b >= n) return;
    size_t ur = (size_t)uidx[b] * DIM + lane;
    size_t ir = (size_t)iidx[b] * DIM + lane;
    size_t sr = (size_t)b * DIM + lane;
    float acc = u0[ur] * i0[ir] + u1[ur] * i1[ir] + u2s[sr] * i2s[sr];
    #pragma unroll
    for (int off = 32; off > 0; off >>= 1) acc += __shfl_xor(acc, off, 64);
    if (lane == 0) out[b] = 1.0f / (1.0f + expf(-acc));
}

// ---------------- launch ----------------

extern "C" void kernel_launch(void* const* d_in, const int* in_sizes, int n_in,
                              void* d_out, int out_size, void* d_ws, size_t ws_size,
                              hipStream_t stream) {
    const float* user_emb = (const float*)d_in[0];
    const float* item_emb = (const float*)d_in[1];
    const float* snii1 = (const float*)d_in[2];
    const float* snii2 = (const float*)d_in[3];
    const float* ciii1 = (const float*)d_in[4];
    const float* ciii2 = (const float*)d_in[5];
    const float* icii1 = (const float*)d_in[6];
    const float* icii2 = (const float*)d_in[7];
    const float* low_w = (const float*)d_in[8];
    const float* low_b = (const float*)d_in[9];
    const float* att1_W = (const float*)d_in[10];
    const float* att1_b = (const float*)d_in[11];
    const float* att2_w = (const float*)d_in[12];
    const float* att2_b = (const float*)d_in[13];
    const int* sn_row = (const int*)d_in[14];
    const int* sn_col = (const int*)d_in[15];
    const int* ci_row = (const int*)d_in[16];
    const int* ci_col = (const int*)d_in[17];
    const int* ic_row = (const int*)d_in[18];
    const int* ic_col = (const int*)d_in[19];
    const int* user_idx = (const int*)d_in[20];
    const int* item_idx = (const int*)d_in[21];
    float* out = (float*)d_out;

    const int Es  = in_sizes[2];
    const int Eui = in_sizes[4];
    const int Eiu = in_sizes[6];
    const int U = in_sizes[0] / DIM;
    const int I = in_sizes[1] / DIM;
    const int B = in_sizes[20];
    const int R = 2 * U + I;           // virtual row space: [0,U)=sn, [U,2U)=ci, [2U,2U+I)=ic
    const int E = Es + Eui + Eiu;

    // ---- workspace carve (4-byte units, 16B-aligned) ----
    char* wsb = (char*)d_ws;
    size_t off = 0;
    auto alloc = [&](size_t n_units) {
        off = (off + 3) & ~(size_t)3;
        void* p = wsb + off * 4; off += n_units; return p;
    };

    int* ptr   = (int*)alloc(R + 1);
    int* cnt   = (int*)alloc(R);
    int* bsum  = (int*)alloc(SCAN_B);
    int* rank  = (int*)alloc(E);
    uint4* rec = (uint4*)alloc((size_t)E * 4);
    float* rs1  = (float*)alloc(R);
    float* rs2  = (float*)alloc(R);
    ushort_t* ub16 = (ushort_t*)alloc((size_t)U * DIM / 2);
    ushort_t* ib16 = (ushort_t*)alloc((size_t)I * DIM / 2);
    float* u1  = (float*)alloc((size_t)U * DIM);
    float* i1  = (float*)alloc((size_t)I * DIM);
    float* u2s = (float*)alloc((size_t)B * DIM);
    float* i2s = (float*)alloc((size_t)B * DIM);
    (void)ws_size;

    // ---- bf16 tables for layer-1 gathers ----
    size_t n4u = (size_t)U * DIM / 4, n4t = (size_t)(U + I) * DIM / 4;
    cvt_kernel<<<(int)((n4t + 255) / 256), 256, 0, stream>>>(user_emb, item_emb,
                                                             ub16, ib16, n4u, n4t);

    // ---- unified CSR build + fused edge logits + softmax ----
    int eb = (E + 255) / 256;
    int nb = (R + SCAN_B - 1) / SCAN_B;    // 489 <= 512
    hipMemsetAsync(cnt, 0, (size_t)R * sizeof(int), stream);
    hist_all<<<eb, 256, 0, stream>>>(sn_row, ci_row, ic_row, cnt, rank, Es, Eui, Eiu, U);
    scan1_kernel<<<nb, SCAN_B, 0, stream>>>(cnt, ptr, bsum, R);
    scan2_kernel<<<1, SCAN_B, 0, stream>>>(bsum, nb);
    scan3_kernel<<<nb, SCAN_B, 0, stream>>>(ptr, bsum, R, E);
    scatter_all<<<eb, 256, 0, stream>>>(sn_row, sn_col, ci_row, ci_col, ic_row, ic_col,
                                        snii1, snii2, ciii1, ciii2, icii1, icii2,
                                        low_w, low_b, ptr, rank, rec,
                                        Es, Eui, Eiu, U);
    softmax_all<<<(R + 15) / 16, 256, 0, stream>>>(rec, ptr, rs1, rs2, R);

    // ---- layer 1 (merged user+item, full) ----
    layer1_kernel<<<(U + I + 3) / 4, 256, 0, stream>>>(ub16, ib16, user_emb, item_emb,
        ptr, rec, rs1, att1_W, att1_b, att2_w, att2_b, u1, i1, U, I);

    // ---- layer 2 (merged, sampled rows only) ----
    layer2_kernel<<<(2 * B + 3) / 4, 256, 0, stream>>>(u1, i1, ptr, rec, rs2,
        att1_W, att1_b, att2_w, att2_b, user_idx, item_idx, u2s, i2s, U, B);

    // ---- final gather-dot-sigmoid ----
    final_kernel<<<(B + 3) / 4, 256, 0, stream>>>(user_emb, u1, u2s, item_emb, i1, i2s,
                                                  user_idx, item_idx, out, B);
}